// Round 7
// baseline (370.218 us; speedup 1.0000x reference)
//
#include <hip/hip_runtime.h>

#define B_ 64
#define NN 1024
#define FF 512

typedef float  fx4 __attribute__((ext_vector_type(4)));
typedef float  fx2 __attribute__((ext_vector_type(2)));
typedef int    ix4 __attribute__((ext_vector_type(4)));
typedef unsigned int   ux4i __attribute__((ext_vector_type(4)));
typedef unsigned int   ux2i __attribute__((ext_vector_type(2)));
typedef unsigned short us4  __attribute__((ext_vector_type(4)));
typedef short  sx8 __attribute__((ext_vector_type(8)));

#define FP8_SCALE   16384.0f        // 2^14: adj*2^14 in [0,16] -> e4m3 normal range
#define INV_SCALE   6.103515625e-5f // 2^-14, folded into B operands (exact)

static __device__ __forceinline__ unsigned short f2bf(float f){
    union { float f; unsigned u; } v; v.f = f;
    unsigned r = v.u + 0x7FFFu + ((v.u >> 16) & 1u);   // RTNE
    return (unsigned short)(r >> 16);
}
static __device__ __forceinline__ float bf2f(unsigned short h){
    union { unsigned u; float f; } v; v.u = ((unsigned)h) << 16;
    return v.f;
}
// one-op packed f32x2 -> bf16x2 (HW RNE); exact for fp8-sourced values
static __device__ __forceinline__ unsigned cvt_pk_bf16(float lo, float hi){
    unsigned r;
    asm("v_cvt_pk_bf16_f32 %0, %1, %2" : "=v"(r) : "v"(lo), "v"(hi));
    return r;
}
static __device__ __forceinline__ sx8 pack_bf16x8(fx4 v0, fx4 v1){
    union { unsigned u[4]; sx8 s; } r;
    r.u[0] = cvt_pk_bf16(v0[0], v0[1]);
    r.u[1] = cvt_pk_bf16(v0[2], v0[3]);
    r.u[2] = cvt_pk_bf16(v1[0], v1[1]);
    r.u[3] = cvt_pk_bf16(v1[2], v1[3]);
    return r.s;
}

// ---------------- u1 = x @ We1 via MFMA, write bf16 transposed [B][32][1024] ----
__global__ __launch_bounds__(512) void k_xw1(
    const float* __restrict__ x, const float* __restrict__ We1,
    unsigned short* __restrict__ u1T){
    __shared__ unsigned short wls[32*512];     // 32 KB
    int tid = threadIdx.x;
    for (int i = tid; i < 32*512; i += 512){
        int col = i >> 9, k = i & 511;
        float v = (col < 30) ? We1[k*30 + col] : 0.f;
        wls[col*512 + ((((k >> 3) ^ (col & 7)) << 3) | (k & 7))] = f2bf(v);
    }
    __syncthreads();
    int w = tid >> 6, l = tid & 63;
    int lr = l & 15, kq = l >> 4;
    int b = blockIdx.y;
    int rowb = blockIdx.x*128 + w*16;          // stripe base within batch
    const float* xp = x + ((size_t)b*NN + rowb + lr)*FF + kq*8;
    fx4 acc0 = {0,0,0,0}, acc1 = {0,0,0,0};
    int c0 = lr, c1 = 16 + lr;
    #pragma unroll 4
    for (int kk = 0; kk < FF; kk += 32){
        fx4 v0 = *(const fx4*)(xp + kk);
        fx4 v1 = *(const fx4*)(xp + kk + 4);
        sx8 a = pack_bf16x8(v0, v1);
        int chunk = (kk >> 3) + kq;
        sx8 b0 = *(const sx8*)(wls + c0*512 + ((chunk ^ (c0 & 7)) << 3));
        sx8 b1 = *(const sx8*)(wls + c1*512 + ((chunk ^ (c1 & 7)) << 3));
        acc0 = __builtin_amdgcn_mfma_f32_16x16x32_bf16(a, b0, acc0, 0, 0, 0);
        acc1 = __builtin_amdgcn_mfma_f32_16x16x32_bf16(a, b1, acc1, 0, 0, 0);
    }
    int row0 = rowb + kq*4;
    us4 o0 = { f2bf(acc0[0]), f2bf(acc0[1]), f2bf(acc0[2]), f2bf(acc0[3]) };
    us4 o1 = { f2bf(acc1[0]), f2bf(acc1[1]), f2bf(acc1[2]), f2bf(acc1[3]) };
    *(us4*)(u1T + ((size_t)b*32 + c0)*NN + row0) = o0;
    *(us4*)(u1T + ((size_t)b*32 + c1)*NN + row0) = o1;
}

// ------- pass 1: h1 = relu(adj @ u1 + be1), adj f32 -> bf16 MFMA + fp8 store ----
__global__ __launch_bounds__(256) void k_cvt_h1(
    const float* __restrict__ adjf, unsigned char* __restrict__ adj8,
    const unsigned short* __restrict__ uT, const float* __restrict__ bias,
    unsigned short* __restrict__ outT){
    __shared__ unsigned short uts[32*NN];  // 64 KB, XOR-swizzled
    int tid = threadIdx.x;
    int rt = blockIdx.x, b = blockIdx.y;
    const ux4i* src = (const ux4i*)(uT + (size_t)b*32*NN);
    #pragma unroll
    for (int i = 0; i < 16; i++){
        int j = tid + i*256;
        int c = j >> 7;
        ux4i v = src[j];
        int dst = (j*16) ^ ((c & 7) << 4);
        *(ux4i*)((char*)uts + dst) = v;
    }
    __syncthreads();
    int w = tid >> 6, l = tid & 63;
    int lr = l & 15, lk = (l >> 4) * 8;
    size_t aoff = (size_t)b*NN*NN + (size_t)(rt*128 + w*32 + lr)*NN + lk;
    int c0 = lr, c1 = 16 + lr;
    fx4 acc00 = {0,0,0,0}, acc01 = {0,0,0,0}, acc10 = {0,0,0,0}, acc11 = {0,0,0,0};
    #pragma unroll 4
    for (int kk = 0; kk < NN; kk += 32){
        fx4 v00 = *(const fx4*)(adjf + aoff + kk);
        fx4 v01 = *(const fx4*)(adjf + aoff + kk + 4);
        fx4 v10 = *(const fx4*)(adjf + aoff + 16*NN + kk);
        fx4 v11 = *(const fx4*)(adjf + aoff + 16*NN + kk + 4);
        sx8 a0 = pack_bf16x8(v00, v01);
        sx8 a1 = pack_bf16x8(v10, v11);
        // fp8 e4m3 store of adj*2^14 (RNE via HW cvt)
        {
            const float S = FP8_SCALE;
            int d0 = __builtin_amdgcn_cvt_pk_fp8_f32(v00[0]*S, v00[1]*S, 0, false);
            d0     = __builtin_amdgcn_cvt_pk_fp8_f32(v00[2]*S, v00[3]*S, d0, true);
            int d1 = __builtin_amdgcn_cvt_pk_fp8_f32(v01[0]*S, v01[1]*S, 0, false);
            d1     = __builtin_amdgcn_cvt_pk_fp8_f32(v01[2]*S, v01[3]*S, d1, true);
            ux2i s0 = { (unsigned)d0, (unsigned)d1 };
            *(ux2i*)(adj8 + aoff + kk) = s0;
            int d2 = __builtin_amdgcn_cvt_pk_fp8_f32(v10[0]*S, v10[1]*S, 0, false);
            d2     = __builtin_amdgcn_cvt_pk_fp8_f32(v10[2]*S, v10[3]*S, d2, true);
            int d3 = __builtin_amdgcn_cvt_pk_fp8_f32(v11[0]*S, v11[1]*S, 0, false);
            d3     = __builtin_amdgcn_cvt_pk_fp8_f32(v11[2]*S, v11[3]*S, d3, true);
            ux2i s1 = { (unsigned)d2, (unsigned)d3 };
            *(ux2i*)(adj8 + aoff + 16*NN + kk) = s1;
        }
        int kb = (kk + lk) * 2;
        sx8 b0 = *(const sx8*)((const char*)uts + ((c0*2048 + kb) ^ ((c0 & 7) << 4)));
        sx8 b1 = *(const sx8*)((const char*)uts + ((c1*2048 + kb) ^ ((c1 & 7) << 4)));
        acc00 = __builtin_amdgcn_mfma_f32_16x16x32_bf16(a0, b0, acc00, 0, 0, 0);
        acc01 = __builtin_amdgcn_mfma_f32_16x16x32_bf16(a0, b1, acc01, 0, 0, 0);
        acc10 = __builtin_amdgcn_mfma_f32_16x16x32_bf16(a1, b0, acc10, 0, 0, 0);
        acc11 = __builtin_amdgcn_mfma_f32_16x16x32_bf16(a1, b1, acc11, 0, 0, 0);
    }
    float bias0 = (c0 < 30) ? bias[c0] : 0.f;
    float bias1 = 0.f;
    if (c1 < 30) bias1 = bias[c1];
    int lq = l >> 4;
    #pragma unroll
    for (int mt = 0; mt < 2; mt++){
        int row0 = rt*128 + w*32 + mt*16 + lq*4;
        fx4 am0 = mt ? acc10 : acc00;
        fx4 am1 = mt ? acc11 : acc01;
        #pragma unroll
        for (int ct = 0; ct < 2; ct++){
            fx4 a = ct ? am1 : am0;
            float bb = ct ? bias1 : bias0;
            int col = ct ? c1 : c0;
            us4 o;
            #pragma unroll
            for (int j = 0; j < 4; j++){
                float v = fmaxf(a[j] + bb, 0.f);   // relu
                o[j] = f2bf(v);
            }
            *(us4*)(outT + ((size_t)b*32 + col)*NN + row0) = o;
        }
    }
}

// ------- fp8 adj pass: out = (2^14*adj_q) @ U_scaled (+bias), oscale on write ----
// adj8: [B][1024][1024] fp8(e4m3, adj*2^14); uT pre-scaled by 2^-14 by producer.
template<int RM>
__global__ __launch_bounds__(256) void k_adjf8(
    const unsigned char* __restrict__ adj8,
    const unsigned short* __restrict__ uT,
    const float* __restrict__ bias, int biasN, float oscale,
    unsigned short* __restrict__ outT){
    __shared__ unsigned short uts[32*NN];  // 64 KB, XOR-swizzled
    int tid = threadIdx.x;
    int rt = blockIdx.x, b = blockIdx.y;
    const ux4i* src = (const ux4i*)(uT + (size_t)b*32*NN);
    #pragma unroll
    for (int i = 0; i < 16; i++){
        int j = tid + i*256;
        int c = j >> 7;
        ux4i v = src[j];
        int dst = (j*16) ^ ((c & 7) << 4);
        *(ux4i*)((char*)uts + dst) = v;
    }
    __syncthreads();
    int w = tid >> 6, l = tid & 63;
    int lr = l & 15, lk = (l >> 4) * 8;
    size_t aoff = (size_t)b*NN*NN + (size_t)(rt*128 + w*32 + lr)*NN + lk;
    int c0 = lr, c1 = 16 + lr;
    fx4 acc00 = {0,0,0,0}, acc01 = {0,0,0,0}, acc10 = {0,0,0,0}, acc11 = {0,0,0,0};
    #pragma unroll 4
    for (int kk = 0; kk < NN; kk += 32){
        ux2i q0 = *(const ux2i*)(adj8 + aoff + kk);
        ux2i q1 = *(const ux2i*)(adj8 + aoff + 16*NN + kk);
        fx2 f0 = __builtin_amdgcn_cvt_pk_f32_fp8((int)q0[0], false);
        fx2 f1 = __builtin_amdgcn_cvt_pk_f32_fp8((int)q0[0], true);
        fx2 f2 = __builtin_amdgcn_cvt_pk_f32_fp8((int)q0[1], false);
        fx2 f3 = __builtin_amdgcn_cvt_pk_f32_fp8((int)q0[1], true);
        fx2 g0 = __builtin_amdgcn_cvt_pk_f32_fp8((int)q1[0], false);
        fx2 g1 = __builtin_amdgcn_cvt_pk_f32_fp8((int)q1[0], true);
        fx2 g2 = __builtin_amdgcn_cvt_pk_f32_fp8((int)q1[1], false);
        fx2 g3 = __builtin_amdgcn_cvt_pk_f32_fp8((int)q1[1], true);
        union { unsigned u[4]; sx8 s; } A0, A1;
        A0.u[0] = cvt_pk_bf16(f0[0], f0[1]);   // exact: fp8 subset of bf16
        A0.u[1] = cvt_pk_bf16(f1[0], f1[1]);
        A0.u[2] = cvt_pk_bf16(f2[0], f2[1]);
        A0.u[3] = cvt_pk_bf16(f3[0], f3[1]);
        A1.u[0] = cvt_pk_bf16(g0[0], g0[1]);
        A1.u[1] = cvt_pk_bf16(g1[0], g1[1]);
        A1.u[2] = cvt_pk_bf16(g2[0], g2[1]);
        A1.u[3] = cvt_pk_bf16(g3[0], g3[1]);
        int kb = (kk + lk) * 2;
        sx8 b0 = *(const sx8*)((const char*)uts + ((c0*2048 + kb) ^ ((c0 & 7) << 4)));
        sx8 b1 = *(const sx8*)((const char*)uts + ((c1*2048 + kb) ^ ((c1 & 7) << 4)));
        acc00 = __builtin_amdgcn_mfma_f32_16x16x32_bf16(A0.s, b0, acc00, 0, 0, 0);
        acc01 = __builtin_amdgcn_mfma_f32_16x16x32_bf16(A0.s, b1, acc01, 0, 0, 0);
        acc10 = __builtin_amdgcn_mfma_f32_16x16x32_bf16(A1.s, b0, acc10, 0, 0, 0);
        acc11 = __builtin_amdgcn_mfma_f32_16x16x32_bf16(A1.s, b1, acc11, 0, 0, 0);
    }
    float bias0 = 0.f, bias1 = 0.f;
    if (bias){
        if (c0 < biasN) bias0 = bias[c0];
        if (c1 < biasN) bias1 = bias[c1];
    }
    int lq = l >> 4;
    #pragma unroll
    for (int mt = 0; mt < 2; mt++){
        int row0 = rt*128 + w*32 + mt*16 + lq*4;
        fx4 am0 = mt ? acc10 : acc00;
        fx4 am1 = mt ? acc11 : acc01;
        #pragma unroll
        for (int ct = 0; ct < 2; ct++){
            fx4 a = ct ? am1 : am0;
            float bb = ct ? bias1 : bias0;
            int col = ct ? c1 : c0;
            us4 o;
            #pragma unroll
            for (int j = 0; j < 4; j++){
                float v = (a[j] + bb) * oscale;
                o[j] = f2bf(v);
            }
            if (RM){
                #pragma unroll
                for (int j = 0; j < 4; j++)
                    outT[((size_t)b*NN + row0 + j)*32 + col] = o[j];
            } else {
                *(us4*)(outT + ((size_t)b*32 + col)*NN + row0) = o;
            }
        }
    }
}

// ---------------- tiny per-row transform: out = act(in @ W + bias) * oscale ------
template<int JI, int CO, bool RELU>
__global__ __launch_bounds__(256) void k_tiny(
    const unsigned short* __restrict__ inT, const float* __restrict__ W,
    const float* __restrict__ bias, float oscale,
    unsigned short* __restrict__ outT){
    int n = blockIdx.x*256 + threadIdx.x;
    int b = blockIdx.y;
    const unsigned short* ip = inT + (size_t)b*32*NN + n;
    float in[JI];
    #pragma unroll
    for (int j = 0; j < JI; j++) in[j] = bf2f(ip[j*NN]);
    float acc[CO];
    #pragma unroll
    for (int c = 0; c < CO; c++) acc[c] = bias ? bias[c] : 0.f;
    #pragma unroll
    for (int j = 0; j < JI; j++){
        #pragma unroll
        for (int c = 0; c < CO; c++) acc[c] += in[j] * W[j*CO + c];
    }
    unsigned short* op = outT + (size_t)b*32*NN + n;
    #pragma unroll
    for (int c = 0; c < 32; c++){
        float v = (c < CO) ? (RELU ? fmaxf(acc[c], 0.f) : acc[c]) * oscale : 0.f;
        op[c*NN] = f2bf(v);
    }
}

// ---- dec = v2 @ Wd2 + bd2 via OPERAND-SWAPPED MFMA: lane holds 4 consecutive ----
// ---- cols of one row -> direct coalesced epilogue, no LDS bounce, no barriers ---
// v2R: [65536][32] bf16 row-major. Wd2^T in LDS bf16 [512 col][32 k], 80B stride.
// mfma(A=Wd2T frag, B=v2 frag): D[m=col][n=row]; lane: row=base+lr, col=16t+kq*4+j.
__global__ __launch_bounds__(512) void k_dec(
    const unsigned short* __restrict__ v2R,
    const float* __restrict__ Wd2, const float* __restrict__ bd2,
    const int* __restrict__ masks, const float* __restrict__ noise,
    float* __restrict__ dec, float* __restrict__ sampled, float* __restrict__ part){
    __shared__ unsigned short wls[512*40];     // 40 KB -> 4 blocks/CU
    __shared__ float red[8];
    int tid = threadIdx.x;
    for (int i = tid; i < 512*32; i += 512){
        int col = i & 511, k = i >> 9;
        float v = (k < 30) ? Wd2[k*512 + col] : 0.f;
        wls[col*40 + k] = f2bf(v);
    }
    __syncthreads();
    int w = tid >> 6, l = tid & 63;
    int lr = l & 15, kq = l >> 4;
    int row = blockIdx.x*128 + w*16 + lr;      // each wave owns 16 rows
    size_t rowoff = (size_t)row * FF;
    sx8 bv = *(const sx8*)(v2R + (size_t)row*32 + kq*8);   // B operand (n=lr)
    int cb = kq*4;                              // lane's column base within a tile
    const float LPC = 2.9930844722234733f;     // -log(sigma) - 0.5*log(2*pi)
    float lpacc = 0.f;
    // ---- tiles t=0,1 : softmax cols 0..31 ----
    fx4 dsm[2];
    #pragma unroll
    for (int t = 0; t < 2; t++){
        sx8 af = *(const sx8*)(wls + (t*16 + lr)*40 + kq*8);
        fx4 acc = {0,0,0,0};
        acc = __builtin_amdgcn_mfma_f32_16x16x32_bf16(af, bv, acc, 0, 0, 0);
        fx4 bi = *(const fx4*)(bd2 + t*16 + cb);
        #pragma unroll
        for (int j = 0; j < 4; j++) dsm[t][j] = acc[j] + bi[j];
    }
    float mx = dsm[0][0];
    #pragma unroll
    for (int j = 1; j < 4; j++) mx = fmaxf(mx, dsm[0][j]);
    #pragma unroll
    for (int j = 0; j < 4; j++) mx = fmaxf(mx, dsm[1][j]);
    mx = fmaxf(mx, __shfl_xor(mx, 16));        // lanes {lr,+16,+32,+48} share a row
    mx = fmaxf(mx, __shfl_xor(mx, 32));
    float e[8], ss = 0.f;
    #pragma unroll
    for (int j = 0; j < 4; j++){ e[j]   = __expf(dsm[0][j] - mx); ss += e[j]; }
    #pragma unroll
    for (int j = 0; j < 4; j++){ e[4+j] = __expf(dsm[1][j] - mx); ss += e[4+j]; }
    ss += __shfl_xor(ss, 16);
    ss += __shfl_xor(ss, 32);
    float inv = 1.f / ss;
    #pragma unroll
    for (int t = 0; t < 2; t++){
        size_t off = rowoff + t*16 + cb;
        ix4 m = *(const ix4*)(masks + off);
        fx4 z = *(const fx4*)(noise + off);
        *(fx4*)(dec + off) = dsm[t];
        fx4 sm;
        #pragma unroll
        for (int j = 0; j < 4; j++){
            float mi = (float)m[j], zi = z[j];
            sm[j] = e[t*4+j]*inv + mi*(0.02f*zi);
            lpacc = fmaf(mi, LPC - 0.5f*zi*zi, lpacc);
        }
        *(fx4*)(sampled + off) = sm;
    }
    // ---- tiles t=2..31 : sigmoid ----
    #pragma unroll 4
    for (int t = 2; t < 32; t++){
        sx8 af = *(const sx8*)(wls + (t*16 + lr)*40 + kq*8);
        fx4 acc = {0,0,0,0};
        acc = __builtin_amdgcn_mfma_f32_16x16x32_bf16(af, bv, acc, 0, 0, 0);
        fx4 bi = *(const fx4*)(bd2 + t*16 + cb);
        size_t off = rowoff + t*16 + cb;
        ix4 m = *(const ix4*)(masks + off);
        fx4 z = *(const fx4*)(noise + off);
        fx4 d, sm;
        #pragma unroll
        for (int j = 0; j < 4; j++){
            d[j] = acc[j] + bi[j];
            float av = 1.f / (1.f + __expf(-d[j]));
            float mi = (float)m[j], zi = z[j];
            sm[j] = av + mi*(0.02f*zi);
            lpacc = fmaf(mi, LPC - 0.5f*zi*zi, lpacc);
        }
        *(fx4*)(dec + off) = d;
        *(fx4*)(sampled + off) = sm;
    }
    // ---- lp reduce ----
    #pragma unroll
    for (int off = 32; off > 0; off >>= 1) lpacc += __shfl_xor(lpacc, off);
    if (l == 0) red[w] = lpacc;
    __syncthreads();
    if (tid == 0){
        float s = 0.f;
        #pragma unroll
        for (int i = 0; i < 8; i++) s += red[i];
        part[blockIdx.x] = s;
    }
}

// ---------------- final: logp[b] = sum of 8 block partials ----------------
__global__ void k_lp(const float* __restrict__ part, float* __restrict__ logp){
    int t = threadIdx.x;   // 64 threads, one per batch
    float s = 0.f;
    #pragma unroll
    for (int i = 0; i < 8; i++) s += part[t*8 + i];
    logp[t] = s;
}

extern "C" void kernel_launch(void* const* d_in, const int* in_sizes, int n_in,
                              void* d_out, int out_size, void* d_ws, size_t ws_size,
                              hipStream_t stream){
    const float* x     = (const float*)d_in[0];
    const float* adj   = (const float*)d_in[1];
    const int*   masks = (const int*)  d_in[2];
    const float* noise = (const float*)d_in[3];
    const float* We1   = (const float*)d_in[4];
    const float* be1   = (const float*)d_in[5];
    const float* We2   = (const float*)d_in[6];
    const float* be2   = (const float*)d_in[7];
    const float* Wd1   = (const float*)d_in[8];
    const float* bd1   = (const float*)d_in[9];
    const float* Wd2   = (const float*)d_in[10];
    const float* bd2   = (const float*)d_in[11];

    float* dec     = (float*)d_out;
    float* sampled = dec + (size_t)B_*NN*FF;
    float* logp    = sampled + (size_t)B_*NN*FF;
    // dec region (134,217,728 B) doubles as fp8-adj scratch (67 MB) until k_dec
    unsigned char* adj8 = (unsigned char*)d_out;
    unsigned short* bufA = (unsigned short*)d_ws;              // 4 MB each
    unsigned short* bufB = bufA + (size_t)B_*32*NN;
    float* part = (float*)bufB;   // reused after h2 is consumed (512 floats)

    k_xw1<<<dim3(8, B_), 512, 0, stream>>>(x, We1, bufA);                                   // u1
    k_cvt_h1<<<dim3(8, B_), 256, 0, stream>>>(adj, adj8, bufA, be1, bufB);                  // h1 (+fp8 cvt)
    k_tiny<30,18,false><<<dim3(4, B_), 256, 0, stream>>>(bufB, We2, nullptr, INV_SCALE, bufA); // u2 (scaled)
    k_adjf8<0><<<dim3(8, B_), 256, 0, stream>>>(adj8, bufA, be2, 18, INV_SCALE, bufB);      // enc (scaled)
    k_adjf8<0><<<dim3(8, B_), 256, 0, stream>>>(adj8, bufB, nullptr, 0, 1.0f, bufA);        // v1 (true)
    k_tiny<18,30,true><<<dim3(4, B_), 256, 0, stream>>>(bufA, Wd1, bd1, INV_SCALE, bufB);   // h2 (scaled)
    k_adjf8<1><<<dim3(8, B_), 256, 0, stream>>>(adj8, bufB, nullptr, 0, 1.0f, bufA);        // v2 row-major
    k_dec<<<512, 512, 0, stream>>>(bufA, Wd2, bd2, masks, noise, dec, sampled, part);
    k_lp<<<1, 64, 0, stream>>>(part, logp);
}

// Round 8
// 336.556 us; speedup vs baseline: 1.1000x; 1.1000x over previous
//
#include <hip/hip_runtime.h>

#define B_ 64
#define NN 1024
#define FF 512

typedef float  fx4 __attribute__((ext_vector_type(4)));
typedef float  fx2 __attribute__((ext_vector_type(2)));
typedef int    ix4 __attribute__((ext_vector_type(4)));
typedef unsigned int   ux4i __attribute__((ext_vector_type(4)));
typedef unsigned int   ux2i __attribute__((ext_vector_type(2)));
typedef unsigned short us4  __attribute__((ext_vector_type(4)));
typedef short  sx8 __attribute__((ext_vector_type(8)));

#define FP8_SCALE   16384.0f        // 2^14: adj*2^14 in [0,16] -> e4m3 normal range
#define INV_SCALE   6.103515625e-5f // 2^-14, folded into B operands (exact)

static __device__ __forceinline__ unsigned short f2bf(float f){
    union { float f; unsigned u; } v; v.f = f;
    unsigned r = v.u + 0x7FFFu + ((v.u >> 16) & 1u);   // RTNE
    return (unsigned short)(r >> 16);
}
static __device__ __forceinline__ float bf2f(unsigned short h){
    union { unsigned u; float f; } v; v.u = ((unsigned)h) << 16;
    return v.f;
}
// one-op packed f32x2 -> bf16x2 (HW RNE); exact for fp8-sourced values
static __device__ __forceinline__ unsigned cvt_pk_bf16(float lo, float hi){
    unsigned r;
    asm("v_cvt_pk_bf16_f32 %0, %1, %2" : "=v"(r) : "v"(lo), "v"(hi));
    return r;
}
static __device__ __forceinline__ sx8 pack_bf16x8(fx4 v0, fx4 v1){
    union { unsigned u[4]; sx8 s; } r;
    r.u[0] = cvt_pk_bf16(v0[0], v0[1]);
    r.u[1] = cvt_pk_bf16(v0[2], v0[3]);
    r.u[2] = cvt_pk_bf16(v1[0], v1[1]);
    r.u[3] = cvt_pk_bf16(v1[2], v1[3]);
    return r.s;
}
template<typename T>
static __device__ __forceinline__ T ntload(const T* p){ return __builtin_nontemporal_load(p); }
static __device__ __forceinline__ void ntstore4(float* p, fx4 v){
    __builtin_nontemporal_store(v, (fx4*)p);
}

// ---------------- u1 = x @ We1 via MFMA, write bf16 transposed [B][32][1024] ----
__global__ __launch_bounds__(512) void k_xw1(
    const float* __restrict__ x, const float* __restrict__ We1,
    unsigned short* __restrict__ u1T){
    __shared__ unsigned short wls[32*512];     // 32 KB
    int tid = threadIdx.x;
    for (int i = tid; i < 32*512; i += 512){
        int col = i >> 9, k = i & 511;
        float v = (col < 30) ? We1[k*30 + col] : 0.f;
        wls[col*512 + ((((k >> 3) ^ (col & 7)) << 3) | (k & 7))] = f2bf(v);
    }
    __syncthreads();
    int w = tid >> 6, l = tid & 63;
    int lr = l & 15, kq = l >> 4;
    int b = blockIdx.y;
    int rowb = blockIdx.x*128 + w*16;          // stripe base within batch
    const float* xp = x + ((size_t)b*NN + rowb + lr)*FF + kq*8;
    fx4 acc0 = {0,0,0,0}, acc1 = {0,0,0,0};
    int c0 = lr, c1 = 16 + lr;
    #pragma unroll 4
    for (int kk = 0; kk < FF; kk += 32){
        fx4 v0 = ntload((const fx4*)(xp + kk));
        fx4 v1 = ntload((const fx4*)(xp + kk + 4));
        sx8 a = pack_bf16x8(v0, v1);
        int chunk = (kk >> 3) + kq;
        sx8 b0 = *(const sx8*)(wls + c0*512 + ((chunk ^ (c0 & 7)) << 3));
        sx8 b1 = *(const sx8*)(wls + c1*512 + ((chunk ^ (c1 & 7)) << 3));
        acc0 = __builtin_amdgcn_mfma_f32_16x16x32_bf16(a, b0, acc0, 0, 0, 0);
        acc1 = __builtin_amdgcn_mfma_f32_16x16x32_bf16(a, b1, acc1, 0, 0, 0);
    }
    int row0 = rowb + kq*4;
    us4 o0 = { f2bf(acc0[0]), f2bf(acc0[1]), f2bf(acc0[2]), f2bf(acc0[3]) };
    us4 o1 = { f2bf(acc1[0]), f2bf(acc1[1]), f2bf(acc1[2]), f2bf(acc1[3]) };
    *(us4*)(u1T + ((size_t)b*32 + c0)*NN + row0) = o0;
    *(us4*)(u1T + ((size_t)b*32 + c1)*NN + row0) = o1;
}

// ------- pass 1: h1 = relu(adj @ u1 + be1), adj f32 -> bf16 MFMA + fp8 store ----
__global__ __launch_bounds__(256) void k_cvt_h1(
    const float* __restrict__ adjf, unsigned char* __restrict__ adj8,
    const unsigned short* __restrict__ uT, const float* __restrict__ bias,
    unsigned short* __restrict__ outT){
    __shared__ unsigned short uts[32*NN];  // 64 KB, XOR-swizzled
    int tid = threadIdx.x;
    int rt = blockIdx.x, b = blockIdx.y;
    const ux4i* src = (const ux4i*)(uT + (size_t)b*32*NN);
    #pragma unroll
    for (int i = 0; i < 16; i++){
        int j = tid + i*256;
        int c = j >> 7;
        ux4i v = src[j];
        int dst = (j*16) ^ ((c & 7) << 4);
        *(ux4i*)((char*)uts + dst) = v;
    }
    __syncthreads();
    int w = tid >> 6, l = tid & 63;
    int lr = l & 15, lk = (l >> 4) * 8;
    size_t aoff = (size_t)b*NN*NN + (size_t)(rt*128 + w*32 + lr)*NN + lk;
    int c0 = lr, c1 = 16 + lr;
    fx4 acc00 = {0,0,0,0}, acc01 = {0,0,0,0}, acc10 = {0,0,0,0}, acc11 = {0,0,0,0};
    #pragma unroll 4
    for (int kk = 0; kk < NN; kk += 32){
        fx4 v00 = ntload((const fx4*)(adjf + aoff + kk));      // nt: streamed once,
        fx4 v01 = ntload((const fx4*)(adjf + aoff + kk + 4));  // keep L3 for adj8
        fx4 v10 = ntload((const fx4*)(adjf + aoff + 16*NN + kk));
        fx4 v11 = ntload((const fx4*)(adjf + aoff + 16*NN + kk + 4));
        sx8 a0 = pack_bf16x8(v00, v01);
        sx8 a1 = pack_bf16x8(v10, v11);
        // fp8 e4m3 store of adj*2^14 (RNE via HW cvt); cacheable (re-read 3x)
        {
            const float S = FP8_SCALE;
            int d0 = __builtin_amdgcn_cvt_pk_fp8_f32(v00[0]*S, v00[1]*S, 0, false);
            d0     = __builtin_amdgcn_cvt_pk_fp8_f32(v00[2]*S, v00[3]*S, d0, true);
            int d1 = __builtin_amdgcn_cvt_pk_fp8_f32(v01[0]*S, v01[1]*S, 0, false);
            d1     = __builtin_amdgcn_cvt_pk_fp8_f32(v01[2]*S, v01[3]*S, d1, true);
            ux2i s0 = { (unsigned)d0, (unsigned)d1 };
            *(ux2i*)(adj8 + aoff + kk) = s0;
            int d2 = __builtin_amdgcn_cvt_pk_fp8_f32(v10[0]*S, v10[1]*S, 0, false);
            d2     = __builtin_amdgcn_cvt_pk_fp8_f32(v10[2]*S, v10[3]*S, d2, true);
            int d3 = __builtin_amdgcn_cvt_pk_fp8_f32(v11[0]*S, v11[1]*S, 0, false);
            d3     = __builtin_amdgcn_cvt_pk_fp8_f32(v11[2]*S, v11[3]*S, d3, true);
            ux2i s1 = { (unsigned)d2, (unsigned)d3 };
            *(ux2i*)(adj8 + aoff + 16*NN + kk) = s1;
        }
        int kb = (kk + lk) * 2;
        sx8 b0 = *(const sx8*)((const char*)uts + ((c0*2048 + kb) ^ ((c0 & 7) << 4)));
        sx8 b1 = *(const sx8*)((const char*)uts + ((c1*2048 + kb) ^ ((c1 & 7) << 4)));
        acc00 = __builtin_amdgcn_mfma_f32_16x16x32_bf16(a0, b0, acc00, 0, 0, 0);
        acc01 = __builtin_amdgcn_mfma_f32_16x16x32_bf16(a0, b1, acc01, 0, 0, 0);
        acc10 = __builtin_amdgcn_mfma_f32_16x16x32_bf16(a1, b0, acc10, 0, 0, 0);
        acc11 = __builtin_amdgcn_mfma_f32_16x16x32_bf16(a1, b1, acc11, 0, 0, 0);
    }
    float bias0 = (c0 < 30) ? bias[c0] : 0.f;
    float bias1 = 0.f;
    if (c1 < 30) bias1 = bias[c1];
    int lq = l >> 4;
    #pragma unroll
    for (int mt = 0; mt < 2; mt++){
        int row0 = rt*128 + w*32 + mt*16 + lq*4;
        fx4 am0 = mt ? acc10 : acc00;
        fx4 am1 = mt ? acc11 : acc01;
        #pragma unroll
        for (int ct = 0; ct < 2; ct++){
            fx4 a = ct ? am1 : am0;
            float bb = ct ? bias1 : bias0;
            int col = ct ? c1 : c0;
            us4 o;
            #pragma unroll
            for (int j = 0; j < 4; j++){
                float v = fmaxf(a[j] + bb, 0.f);   // relu
                o[j] = f2bf(v);
            }
            *(us4*)(outT + ((size_t)b*32 + col)*NN + row0) = o;
        }
    }
}

// ------- fp8 adj pass: out = (2^14*adj_q) @ U_scaled (+bias), oscale on write ----
// adj8: [B][1024][1024] fp8(e4m3, adj*2^14); uT pre-scaled by 2^-14 by producer.
template<int RM>
__global__ __launch_bounds__(256) void k_adjf8(
    const unsigned char* __restrict__ adj8,
    const unsigned short* __restrict__ uT,
    const float* __restrict__ bias, int biasN, float oscale,
    unsigned short* __restrict__ outT){
    __shared__ unsigned short uts[32*NN];  // 64 KB, XOR-swizzled
    int tid = threadIdx.x;
    int rt = blockIdx.x, b = blockIdx.y;
    const ux4i* src = (const ux4i*)(uT + (size_t)b*32*NN);
    #pragma unroll
    for (int i = 0; i < 16; i++){
        int j = tid + i*256;
        int c = j >> 7;
        ux4i v = src[j];
        int dst = (j*16) ^ ((c & 7) << 4);
        *(ux4i*)((char*)uts + dst) = v;
    }
    __syncthreads();
    int w = tid >> 6, l = tid & 63;
    int lr = l & 15, lk = (l >> 4) * 8;
    size_t aoff = (size_t)b*NN*NN + (size_t)(rt*128 + w*32 + lr)*NN + lk;
    int c0 = lr, c1 = 16 + lr;
    fx4 acc00 = {0,0,0,0}, acc01 = {0,0,0,0}, acc10 = {0,0,0,0}, acc11 = {0,0,0,0};
    #pragma unroll 4
    for (int kk = 0; kk < NN; kk += 32){
        ux2i q0 = *(const ux2i*)(adj8 + aoff + kk);
        ux2i q1 = *(const ux2i*)(adj8 + aoff + 16*NN + kk);
        fx2 f0 = __builtin_amdgcn_cvt_pk_f32_fp8((int)q0[0], false);
        fx2 f1 = __builtin_amdgcn_cvt_pk_f32_fp8((int)q0[0], true);
        fx2 f2 = __builtin_amdgcn_cvt_pk_f32_fp8((int)q0[1], false);
        fx2 f3 = __builtin_amdgcn_cvt_pk_f32_fp8((int)q0[1], true);
        fx2 g0 = __builtin_amdgcn_cvt_pk_f32_fp8((int)q1[0], false);
        fx2 g1 = __builtin_amdgcn_cvt_pk_f32_fp8((int)q1[0], true);
        fx2 g2 = __builtin_amdgcn_cvt_pk_f32_fp8((int)q1[1], false);
        fx2 g3 = __builtin_amdgcn_cvt_pk_f32_fp8((int)q1[1], true);
        union { unsigned u[4]; sx8 s; } A0, A1;
        A0.u[0] = cvt_pk_bf16(f0[0], f0[1]);   // exact: fp8 subset of bf16
        A0.u[1] = cvt_pk_bf16(f1[0], f1[1]);
        A0.u[2] = cvt_pk_bf16(f2[0], f2[1]);
        A0.u[3] = cvt_pk_bf16(f3[0], f3[1]);
        A1.u[0] = cvt_pk_bf16(g0[0], g0[1]);
        A1.u[1] = cvt_pk_bf16(g1[0], g1[1]);
        A1.u[2] = cvt_pk_bf16(g2[0], g2[1]);
        A1.u[3] = cvt_pk_bf16(g3[0], g3[1]);
        int kb = (kk + lk) * 2;
        sx8 b0 = *(const sx8*)((const char*)uts + ((c0*2048 + kb) ^ ((c0 & 7) << 4)));
        sx8 b1 = *(const sx8*)((const char*)uts + ((c1*2048 + kb) ^ ((c1 & 7) << 4)));
        acc00 = __builtin_amdgcn_mfma_f32_16x16x32_bf16(A0.s, b0, acc00, 0, 0, 0);
        acc01 = __builtin_amdgcn_mfma_f32_16x16x32_bf16(A0.s, b1, acc01, 0, 0, 0);
        acc10 = __builtin_amdgcn_mfma_f32_16x16x32_bf16(A1.s, b0, acc10, 0, 0, 0);
        acc11 = __builtin_amdgcn_mfma_f32_16x16x32_bf16(A1.s, b1, acc11, 0, 0, 0);
    }
    float bias0 = 0.f, bias1 = 0.f;
    if (bias){
        if (c0 < biasN) bias0 = bias[c0];
        if (c1 < biasN) bias1 = bias[c1];
    }
    int lq = l >> 4;
    #pragma unroll
    for (int mt = 0; mt < 2; mt++){
        int row0 = rt*128 + w*32 + mt*16 + lq*4;
        fx4 am0 = mt ? acc10 : acc00;
        fx4 am1 = mt ? acc11 : acc01;
        #pragma unroll
        for (int ct = 0; ct < 2; ct++){
            fx4 a = ct ? am1 : am0;
            float bb = ct ? bias1 : bias0;
            int col = ct ? c1 : c0;
            us4 o;
            #pragma unroll
            for (int j = 0; j < 4; j++){
                float v = (a[j] + bb) * oscale;
                o[j] = f2bf(v);
            }
            if (RM){
                #pragma unroll
                for (int j = 0; j < 4; j++)
                    outT[((size_t)b*NN + row0 + j)*32 + col] = o[j];
            } else {
                *(us4*)(outT + ((size_t)b*32 + col)*NN + row0) = o;
            }
        }
    }
}

// ---------------- tiny per-row transform: out = act(in @ W + bias) * oscale ------
template<int JI, int CO, bool RELU>
__global__ __launch_bounds__(256) void k_tiny(
    const unsigned short* __restrict__ inT, const float* __restrict__ W,
    const float* __restrict__ bias, float oscale,
    unsigned short* __restrict__ outT){
    int n = blockIdx.x*256 + threadIdx.x;
    int b = blockIdx.y;
    const unsigned short* ip = inT + (size_t)b*32*NN + n;
    float in[JI];
    #pragma unroll
    for (int j = 0; j < JI; j++) in[j] = bf2f(ip[j*NN]);
    float acc[CO];
    #pragma unroll
    for (int c = 0; c < CO; c++) acc[c] = bias ? bias[c] : 0.f;
    #pragma unroll
    for (int j = 0; j < JI; j++){
        #pragma unroll
        for (int c = 0; c < CO; c++) acc[c] += in[j] * W[j*CO + c];
    }
    unsigned short* op = outT + (size_t)b*32*NN + n;
    #pragma unroll
    for (int c = 0; c < 32; c++){
        float v = (c < CO) ? (RELU ? fmaxf(acc[c], 0.f) : acc[c]) * oscale : 0.f;
        op[c*NN] = f2bf(v);
    }
}

// ---------------- dec = v2 @ Wd2 + bd2 via MFMA ; LDS bounce ; coalesced stream --
// m/z loads hoisted to stripe top (latency hides under MFMA phase); nt streaming.
__global__ __launch_bounds__(512, 2) void k_dec(
    const unsigned short* __restrict__ v2R,
    const float* __restrict__ Wd2, const float* __restrict__ bd2,
    const int* __restrict__ masks, const float* __restrict__ noise,
    float* __restrict__ dec, float* __restrict__ sampled, float* __restrict__ part){
    __shared__ unsigned short wls[512*40];     // 40960 B
    __shared__ float dls[16][516];             // 33024 B
    __shared__ float red[8];
    int tid = threadIdx.x;
    for (int i = tid; i < 512*32; i += 512){
        int col = i & 511, k = i >> 9;
        float v = (k < 30) ? Wd2[k*512 + col] : 0.f;
        wls[col*40 + k] = f2bf(v);
    }
    int w = tid >> 6, l = tid & 63;
    int lr = l & 15, kq = l >> 4;
    const float LPC = 2.9930844722234733f;     // -log(sigma) - 0.5*log(2*pi)
    float lpacc = 0.f;
    __syncthreads();
    #pragma unroll
    for (int it = 0; it < 4; it++){
        int rbase = blockIdx.x*64 + it*16;
        // ---- issue this stripe's streaming loads EARLY (hide under MFMA) ----
        size_t offA = (size_t)(rbase + w)*FF + l*8;
        size_t offB = (size_t)(rbase + w + 8)*FF + l*8;
        ix4 mA0 = ntload((const ix4*)(masks + offA));
        ix4 mA1 = ntload((const ix4*)(masks + offA + 4));
        fx4 zA0 = ntload((const fx4*)(noise + offA));
        fx4 zA1 = ntload((const fx4*)(noise + offA + 4));
        ix4 mB0 = ntload((const ix4*)(masks + offB));
        ix4 mB1 = ntload((const ix4*)(masks + offB + 4));
        fx4 zB0 = ntload((const fx4*)(noise + offB));
        fx4 zB1 = ntload((const fx4*)(noise + offB + 4));
        // ---- MFMA phase: d[16][512] into LDS ----
        sx8 a = *(const sx8*)(v2R + (size_t)(rbase + lr)*32 + kq*8);
        #pragma unroll
        for (int i = 0; i < 4; i++){
            int c = (w + 8*i)*16 + lr;
            sx8 bb = *(const sx8*)(wls + c*40 + kq*8);
            fx4 acc = {0,0,0,0};
            acc = __builtin_amdgcn_mfma_f32_16x16x32_bf16(a, bb, acc, 0, 0, 0);
            float bi = bd2[c];
            #pragma unroll
            for (int j = 0; j < 4; j++)
                dls[kq*4 + j][c] = acc[j] + bi;
        }
        __syncthreads();
        // ---- stream phase: wave w handles rows w (A) and w+8 (B) ----
        #pragma unroll
        for (int s = 0; s < 2; s++){
            int rloc = s ? (w + 8) : w;
            size_t off = s ? offB : offA;
            ix4 m0 = s ? mB0 : mA0;  ix4 m1 = s ? mB1 : mA1;
            fx4 z0 = s ? zB0 : zA0;  fx4 z1 = s ? zB1 : zA1;
            fx4 d0 = *(const fx4*)&dls[rloc][l*8];
            fx4 d1 = *(const fx4*)&dls[rloc][l*8 + 4];
            float av[8];
            #pragma unroll
            for (int i = 0; i < 4; i++){
                av[i]   = 1.f/(1.f + __expf(-d0[i]));
                av[4+i] = 1.f/(1.f + __expf(-d1[i]));
            }
            if (l < 4){                        // cols 0..31 -> softmax
                float mx = d0[0];
                #pragma unroll
                for (int i = 1; i < 4; i++) mx = fmaxf(mx, d0[i]);
                #pragma unroll
                for (int i = 0; i < 4; i++) mx = fmaxf(mx, d1[i]);
                mx = fmaxf(mx, __shfl_xor(mx, 1, 4));
                mx = fmaxf(mx, __shfl_xor(mx, 2, 4));
                float e[8], ss = 0.f;
                #pragma unroll
                for (int i = 0; i < 4; i++){ e[i] = __expf(d0[i] - mx); ss += e[i]; }
                #pragma unroll
                for (int i = 0; i < 4; i++){ e[4+i] = __expf(d1[i] - mx); ss += e[4+i]; }
                ss += __shfl_xor(ss, 1, 4);
                ss += __shfl_xor(ss, 2, 4);
                float inv = 1.f / ss;
                #pragma unroll
                for (int i = 0; i < 8; i++) av[i] = e[i]*inv;
            }
            ntstore4(dec + off,     d0);
            ntstore4(dec + off + 4, d1);
            fx4 sm0, sm1;
            #pragma unroll
            for (int i = 0; i < 4; i++){
                float mi0 = (float)m0[i], zi0 = z0[i];
                float mi1 = (float)m1[i], zi1 = z1[i];
                sm0[i] = av[i]   + mi0*(0.02f*zi0);
                sm1[i] = av[4+i] + mi1*(0.02f*zi1);
                lpacc = fmaf(mi0, LPC - 0.5f*zi0*zi0, lpacc);
                lpacc = fmaf(mi1, LPC - 0.5f*zi1*zi1, lpacc);
            }
            ntstore4(sampled + off,     sm0);
            ntstore4(sampled + off + 4, sm1);
        }
        __syncthreads();
    }
    #pragma unroll
    for (int off = 32; off > 0; off >>= 1) lpacc += __shfl_xor(lpacc, off);
    if (l == 0) red[w] = lpacc;
    __syncthreads();
    if (tid == 0){
        float s = 0.f;
        #pragma unroll
        for (int i = 0; i < 8; i++) s += red[i];
        part[blockIdx.x] = s;
    }
}

// ---------------- final: logp[b] = sum of 16 block partials ----------------
__global__ void k_lp(const float* __restrict__ part, float* __restrict__ logp){
    int t = threadIdx.x;   // 64 threads, one per batch
    float s = 0.f;
    #pragma unroll
    for (int i = 0; i < 16; i++) s += part[t*16 + i];
    logp[t] = s;
}

extern "C" void kernel_launch(void* const* d_in, const int* in_sizes, int n_in,
                              void* d_out, int out_size, void* d_ws, size_t ws_size,
                              hipStream_t stream){
    const float* x     = (const float*)d_in[0];
    const float* adj   = (const float*)d_in[1];
    const int*   masks = (const int*)  d_in[2];
    const float* noise = (const float*)d_in[3];
    const float* We1   = (const float*)d_in[4];
    const float* be1   = (const float*)d_in[5];
    const float* We2   = (const float*)d_in[6];
    const float* be2   = (const float*)d_in[7];
    const float* Wd1   = (const float*)d_in[8];
    const float* bd1   = (const float*)d_in[9];
    const float* Wd2   = (const float*)d_in[10];
    const float* bd2   = (const float*)d_in[11];

    float* dec     = (float*)d_out;
    float* sampled = dec + (size_t)B_*NN*FF;
    float* logp    = sampled + (size_t)B_*NN*FF;
    // dec region (134,217,728 B) doubles as fp8-adj scratch (67 MB) until k_dec
    unsigned char* adj8 = (unsigned char*)d_out;
    unsigned short* bufA = (unsigned short*)d_ws;              // 4 MB each
    unsigned short* bufB = bufA + (size_t)B_*32*NN;
    float* part = (float*)bufB;   // reused after h2 is consumed (1024 floats)

    k_xw1<<<dim3(8, B_), 512, 0, stream>>>(x, We1, bufA);                                   // u1
    k_cvt_h1<<<dim3(8, B_), 256, 0, stream>>>(adj, adj8, bufA, be1, bufB);                  // h1 (+fp8 cvt)
    k_tiny<30,18,false><<<dim3(4, B_), 256, 0, stream>>>(bufB, We2, nullptr, INV_SCALE, bufA); // u2 (scaled)
    k_adjf8<0><<<dim3(8, B_), 256, 0, stream>>>(adj8, bufA, be2, 18, INV_SCALE, bufB);      // enc (scaled)
    k_adjf8<0><<<dim3(8, B_), 256, 0, stream>>>(adj8, bufB, nullptr, 0, 1.0f, bufA);        // v1 (true)
    k_tiny<18,30,true><<<dim3(4, B_), 256, 0, stream>>>(bufA, Wd1, bd1, INV_SCALE, bufB);   // h2 (scaled)
    k_adjf8<1><<<dim3(8, B_), 256, 0, stream>>>(adj8, bufB, nullptr, 0, 1.0f, bufA);        // v2 row-major
    k_dec<<<1024, 512, 0, stream>>>(bufA, Wd2, bd2, masks, noise, dec, sampled, part);
    k_lp<<<1, 64, 0, stream>>>(part, logp);
}

// Round 9
// 328.745 us; speedup vs baseline: 1.1262x; 1.0238x over previous
//
#include <hip/hip_runtime.h>

#define B_ 64
#define NN 1024
#define FF 512

typedef float  fx4 __attribute__((ext_vector_type(4)));
typedef float  fx2 __attribute__((ext_vector_type(2)));
typedef int    ix4 __attribute__((ext_vector_type(4)));
typedef unsigned int   ux4i __attribute__((ext_vector_type(4)));
typedef unsigned int   ux2i __attribute__((ext_vector_type(2)));
typedef unsigned short us4  __attribute__((ext_vector_type(4)));
typedef short  sx8 __attribute__((ext_vector_type(8)));

#define FP8_SCALE   16384.0f        // 2^14: adj*2^14 in [0,16] -> e4m3 normal range
#define INV_SCALE   6.103515625e-5f // 2^-14, folded into operands (exact pow2)

static __device__ __forceinline__ unsigned short f2bf(float f){
    union { float f; unsigned u; } v; v.f = f;
    unsigned r = v.u + 0x7FFFu + ((v.u >> 16) & 1u);   // RTNE
    return (unsigned short)(r >> 16);
}
static __device__ __forceinline__ float bf2f(unsigned short h){
    union { unsigned u; float f; } v; v.u = ((unsigned)h) << 16;
    return v.f;
}
static __device__ __forceinline__ unsigned cvt_pk_bf16(float lo, float hi){
    unsigned r;
    asm("v_cvt_pk_bf16_f32 %0, %1, %2" : "=v"(r) : "v"(lo), "v"(hi));
    return r;
}
static __device__ __forceinline__ sx8 pack_bf16x8(fx4 v0, fx4 v1){
    union { unsigned u[4]; sx8 s; } r;
    r.u[0] = cvt_pk_bf16(v0[0], v0[1]);
    r.u[1] = cvt_pk_bf16(v0[2], v0[3]);
    r.u[2] = cvt_pk_bf16(v1[0], v1[1]);
    r.u[3] = cvt_pk_bf16(v1[2], v1[3]);
    return r.s;
}
template<typename T>
static __device__ __forceinline__ T ntload(const T* p){ return __builtin_nontemporal_load(p); }
static __device__ __forceinline__ void ntstore4(float* p, fx4 v){
    __builtin_nontemporal_store(v, (fx4*)p);
}

// ---------------- u1 = x @ We1 via MFMA, write bf16 transposed [B][32][1024] ----
__global__ __launch_bounds__(512) void k_xw1(
    const float* __restrict__ x, const float* __restrict__ We1,
    unsigned short* __restrict__ u1T){
    __shared__ unsigned short wls[32*512];     // 32 KB
    int tid = threadIdx.x;
    for (int i = tid; i < 32*512; i += 512){
        int col = i >> 9, k = i & 511;
        float v = (col < 30) ? We1[k*30 + col] : 0.f;
        wls[col*512 + ((((k >> 3) ^ (col & 7)) << 3) | (k & 7))] = f2bf(v);
    }
    __syncthreads();
    int w = tid >> 6, l = tid & 63;
    int lr = l & 15, kq = l >> 4;
    int b = blockIdx.y;
    int rowb = blockIdx.x*128 + w*16;
    const float* xp = x + ((size_t)b*NN + rowb + lr)*FF + kq*8;
    fx4 acc0 = {0,0,0,0}, acc1 = {0,0,0,0};
    int c0 = lr, c1 = 16 + lr;
    #pragma unroll 4
    for (int kk = 0; kk < FF; kk += 32){
        fx4 v0 = ntload((const fx4*)(xp + kk));
        fx4 v1 = ntload((const fx4*)(xp + kk + 4));
        sx8 a = pack_bf16x8(v0, v1);
        int chunk = (kk >> 3) + kq;
        sx8 b0 = *(const sx8*)(wls + c0*512 + ((chunk ^ (c0 & 7)) << 3));
        sx8 b1 = *(const sx8*)(wls + c1*512 + ((chunk ^ (c1 & 7)) << 3));
        acc0 = __builtin_amdgcn_mfma_f32_16x16x32_bf16(a, b0, acc0, 0, 0, 0);
        acc1 = __builtin_amdgcn_mfma_f32_16x16x32_bf16(a, b1, acc1, 0, 0, 0);
    }
    int row0 = rowb + kq*4;
    us4 o0 = { f2bf(acc0[0]), f2bf(acc0[1]), f2bf(acc0[2]), f2bf(acc0[3]) };
    us4 o1 = { f2bf(acc1[0]), f2bf(acc1[1]), f2bf(acc1[2]), f2bf(acc1[3]) };
    *(us4*)(u1T + ((size_t)b*32 + c0)*NN + row0) = o0;
    *(us4*)(u1T + ((size_t)b*32 + c1)*NN + row0) = o1;
}

// -- pass 1 fused: h1 = relu(adj@u1+be1) (LDS only) ; u2 = h1@We2 * 2^-14 -> u2T --
__global__ __launch_bounds__(256) void k_cvt_h1u2(
    const float* __restrict__ adjf, unsigned char* __restrict__ adj8,
    const unsigned short* __restrict__ uT, const float* __restrict__ be1,
    const float* __restrict__ We2, unsigned short* __restrict__ u2T){
    __shared__ unsigned short uts[32*NN];      // 64 KB
    __shared__ unsigned short hls[128][34];    // 8704 B
    __shared__ float wels[540];                // We2 30x18
    int tid = threadIdx.x;
    int rt = blockIdx.x, b = blockIdx.y;
    for (int i = tid; i < 540; i += 256) wels[i] = We2[i];
    const ux4i* src = (const ux4i*)(uT + (size_t)b*32*NN);
    #pragma unroll
    for (int i = 0; i < 16; i++){
        int j = tid + i*256;
        int c = j >> 7;
        ux4i v = src[j];
        *(ux4i*)((char*)uts + ((j*16) ^ ((c & 7) << 4))) = v;
    }
    __syncthreads();
    int w = tid >> 6, l = tid & 63;
    int lr = l & 15, lk = (l >> 4) * 8;
    size_t aoff = (size_t)b*NN*NN + (size_t)(rt*128 + w*32 + lr)*NN + lk;
    int c0 = lr, c1 = 16 + lr;
    fx4 acc00 = {0,0,0,0}, acc01 = {0,0,0,0}, acc10 = {0,0,0,0}, acc11 = {0,0,0,0};
    #pragma unroll 4
    for (int kk = 0; kk < NN; kk += 32){
        fx4 v00 = ntload((const fx4*)(adjf + aoff + kk));
        fx4 v01 = ntload((const fx4*)(adjf + aoff + kk + 4));
        fx4 v10 = ntload((const fx4*)(adjf + aoff + 16*NN + kk));
        fx4 v11 = ntload((const fx4*)(adjf + aoff + 16*NN + kk + 4));
        sx8 a0 = pack_bf16x8(v00, v01);
        sx8 a1 = pack_bf16x8(v10, v11);
        {
            const float S = FP8_SCALE;
            int d0 = __builtin_amdgcn_cvt_pk_fp8_f32(v00[0]*S, v00[1]*S, 0, false);
            d0     = __builtin_amdgcn_cvt_pk_fp8_f32(v00[2]*S, v00[3]*S, d0, true);
            int d1 = __builtin_amdgcn_cvt_pk_fp8_f32(v01[0]*S, v01[1]*S, 0, false);
            d1     = __builtin_amdgcn_cvt_pk_fp8_f32(v01[2]*S, v01[3]*S, d1, true);
            ux2i s0 = { (unsigned)d0, (unsigned)d1 };
            *(ux2i*)(adj8 + aoff + kk) = s0;
            int d2 = __builtin_amdgcn_cvt_pk_fp8_f32(v10[0]*S, v10[1]*S, 0, false);
            d2     = __builtin_amdgcn_cvt_pk_fp8_f32(v10[2]*S, v10[3]*S, d2, true);
            int d3 = __builtin_amdgcn_cvt_pk_fp8_f32(v11[0]*S, v11[1]*S, 0, false);
            d3     = __builtin_amdgcn_cvt_pk_fp8_f32(v11[2]*S, v11[3]*S, d3, true);
            ux2i s1 = { (unsigned)d2, (unsigned)d3 };
            *(ux2i*)(adj8 + aoff + 16*NN + kk) = s1;
        }
        int kb = (kk + lk) * 2;
        sx8 b0 = *(const sx8*)((const char*)uts + ((c0*2048 + kb) ^ ((c0 & 7) << 4)));
        sx8 b1 = *(const sx8*)((const char*)uts + ((c1*2048 + kb) ^ ((c1 & 7) << 4)));
        acc00 = __builtin_amdgcn_mfma_f32_16x16x32_bf16(a0, b0, acc00, 0, 0, 0);
        acc01 = __builtin_amdgcn_mfma_f32_16x16x32_bf16(a0, b1, acc01, 0, 0, 0);
        acc10 = __builtin_amdgcn_mfma_f32_16x16x32_bf16(a1, b0, acc10, 0, 0, 0);
        acc11 = __builtin_amdgcn_mfma_f32_16x16x32_bf16(a1, b1, acc11, 0, 0, 0);
    }
    float bias0 = (c0 < 30) ? be1[c0] : 0.f;
    float bias1 = (c1 < 30) ? be1[c1] : 0.f;
    int lq = l >> 4;
    #pragma unroll
    for (int mt = 0; mt < 2; mt++){
        int rl0 = w*32 + mt*16 + lq*4;
        fx4 am0 = mt ? acc10 : acc00;
        fx4 am1 = mt ? acc11 : acc01;
        #pragma unroll
        for (int ct = 0; ct < 2; ct++){
            fx4 a = ct ? am1 : am0;
            float bb = ct ? bias1 : bias0;
            int col = ct ? c1 : c0;
            #pragma unroll
            for (int j = 0; j < 4; j++)
                hls[rl0 + j][col] = f2bf(fmaxf(a[j] + bb, 0.f));
        }
    }
    __syncthreads();
    // u2 = h1 @ We2, scaled 2^-14; rows split 2 threads/row, 9 cols each
    int row = tid >> 1, half = tid & 1;
    float h[30];
    #pragma unroll
    for (int j = 0; j < 30; j++) h[j] = bf2f(hls[row][j]);
    float acc2[9] = {0,0,0,0,0,0,0,0,0};
    #pragma unroll
    for (int j = 0; j < 30; j++){
        #pragma unroll
        for (int c = 0; c < 9; c++) acc2[c] += h[j]*wels[j*18 + half*9 + c];
    }
    unsigned short* base = u2T + (size_t)b*32*NN + rt*128 + row;
    #pragma unroll
    for (int c = 0; c < 9; c++)
        base[(size_t)(half*9 + c)*NN] = f2bf(acc2[c]*INV_SCALE);
    #pragma unroll
    for (int i = 0; i < 7; i++)
        base[(size_t)(18 + half*7 + i)*NN] = 0;   // zero pad cols 18..31
}

// ------- fp8 adj pass: out = (2^14*adj_q) @ U_scaled (+bias), oscale on write ----
template<int RM>
__global__ __launch_bounds__(256) void k_adjf8(
    const unsigned char* __restrict__ adj8,
    const unsigned short* __restrict__ uT,
    const float* __restrict__ bias, int biasN, float oscale,
    unsigned short* __restrict__ outT){
    __shared__ unsigned short uts[32*NN];
    int tid = threadIdx.x;
    int rt = blockIdx.x, b = blockIdx.y;
    const ux4i* src = (const ux4i*)(uT + (size_t)b*32*NN);
    #pragma unroll
    for (int i = 0; i < 16; i++){
        int j = tid + i*256;
        int c = j >> 7;
        ux4i v = src[j];
        *(ux4i*)((char*)uts + ((j*16) ^ ((c & 7) << 4))) = v;
    }
    __syncthreads();
    int w = tid >> 6, l = tid & 63;
    int lr = l & 15, lk = (l >> 4) * 8;
    size_t aoff = (size_t)b*NN*NN + (size_t)(rt*128 + w*32 + lr)*NN + lk;
    int c0 = lr, c1 = 16 + lr;
    fx4 acc00 = {0,0,0,0}, acc01 = {0,0,0,0}, acc10 = {0,0,0,0}, acc11 = {0,0,0,0};
    #pragma unroll 4
    for (int kk = 0; kk < NN; kk += 32){
        ux2i q0 = *(const ux2i*)(adj8 + aoff + kk);
        ux2i q1 = *(const ux2i*)(adj8 + aoff + 16*NN + kk);
        fx2 f0 = __builtin_amdgcn_cvt_pk_f32_fp8((int)q0[0], false);
        fx2 f1 = __builtin_amdgcn_cvt_pk_f32_fp8((int)q0[0], true);
        fx2 f2 = __builtin_amdgcn_cvt_pk_f32_fp8((int)q0[1], false);
        fx2 f3 = __builtin_amdgcn_cvt_pk_f32_fp8((int)q0[1], true);
        fx2 g0 = __builtin_amdgcn_cvt_pk_f32_fp8((int)q1[0], false);
        fx2 g1 = __builtin_amdgcn_cvt_pk_f32_fp8((int)q1[0], true);
        fx2 g2 = __builtin_amdgcn_cvt_pk_f32_fp8((int)q1[1], false);
        fx2 g3 = __builtin_amdgcn_cvt_pk_f32_fp8((int)q1[1], true);
        union { unsigned u[4]; sx8 s; } A0, A1;
        A0.u[0] = cvt_pk_bf16(f0[0], f0[1]);
        A0.u[1] = cvt_pk_bf16(f1[0], f1[1]);
        A0.u[2] = cvt_pk_bf16(f2[0], f2[1]);
        A0.u[3] = cvt_pk_bf16(f3[0], f3[1]);
        A1.u[0] = cvt_pk_bf16(g0[0], g0[1]);
        A1.u[1] = cvt_pk_bf16(g1[0], g1[1]);
        A1.u[2] = cvt_pk_bf16(g2[0], g2[1]);
        A1.u[3] = cvt_pk_bf16(g3[0], g3[1]);
        int kb = (kk + lk) * 2;
        sx8 b0 = *(const sx8*)((const char*)uts + ((c0*2048 + kb) ^ ((c0 & 7) << 4)));
        sx8 b1 = *(const sx8*)((const char*)uts + ((c1*2048 + kb) ^ ((c1 & 7) << 4)));
        acc00 = __builtin_amdgcn_mfma_f32_16x16x32_bf16(A0.s, b0, acc00, 0, 0, 0);
        acc01 = __builtin_amdgcn_mfma_f32_16x16x32_bf16(A0.s, b1, acc01, 0, 0, 0);
        acc10 = __builtin_amdgcn_mfma_f32_16x16x32_bf16(A1.s, b0, acc10, 0, 0, 0);
        acc11 = __builtin_amdgcn_mfma_f32_16x16x32_bf16(A1.s, b1, acc11, 0, 0, 0);
    }
    float bias0 = 0.f, bias1 = 0.f;
    if (bias){
        if (c0 < biasN) bias0 = bias[c0];
        if (c1 < biasN) bias1 = bias[c1];
    }
    int lq = l >> 4;
    #pragma unroll
    for (int mt = 0; mt < 2; mt++){
        int row0 = rt*128 + w*32 + mt*16 + lq*4;
        fx4 am0 = mt ? acc10 : acc00;
        fx4 am1 = mt ? acc11 : acc01;
        #pragma unroll
        for (int ct = 0; ct < 2; ct++){
            fx4 a = ct ? am1 : am0;
            float bb = ct ? bias1 : bias0;
            int col = ct ? c1 : c0;
            us4 o;
            #pragma unroll
            for (int j = 0; j < 4; j++){
                float v = (a[j] + bb) * oscale;
                o[j] = f2bf(v);
            }
            if (RM){
                #pragma unroll
                for (int j = 0; j < 4; j++)
                    outT[((size_t)b*NN + row0 + j)*32 + col] = o[j];
            } else {
                *(us4*)(outT + ((size_t)b*32 + col)*NN + row0) = o;
            }
        }
    }
}

// -- v1 pass fused: v1 = adj@enc (LDS only) ; h2 = relu(v1@Wd1+bd1)*2^-14 -> h2T --
__global__ __launch_bounds__(256) void k_v1h2(
    const unsigned char* __restrict__ adj8,
    const unsigned short* __restrict__ encT,
    const float* __restrict__ Wd1, const float* __restrict__ bd1,
    unsigned short* __restrict__ h2T){
    __shared__ unsigned short uts[32*NN];
    __shared__ unsigned short vls[128][34];
    __shared__ float wd[540];                  // Wd1 18x30
    __shared__ float bdl[30];
    int tid = threadIdx.x;
    int rt = blockIdx.x, b = blockIdx.y;
    for (int i = tid; i < 540; i += 256) wd[i] = Wd1[i];
    if (tid < 30) bdl[tid] = bd1[tid];
    const ux4i* src = (const ux4i*)(encT + (size_t)b*32*NN);
    #pragma unroll
    for (int i = 0; i < 16; i++){
        int j = tid + i*256;
        int c = j >> 7;
        ux4i v = src[j];
        *(ux4i*)((char*)uts + ((j*16) ^ ((c & 7) << 4))) = v;
    }
    __syncthreads();
    int w = tid >> 6, l = tid & 63;
    int lr = l & 15, lk = (l >> 4) * 8;
    size_t aoff = (size_t)b*NN*NN + (size_t)(rt*128 + w*32 + lr)*NN + lk;
    int c0 = lr, c1 = 16 + lr;
    fx4 acc00 = {0,0,0,0}, acc01 = {0,0,0,0}, acc10 = {0,0,0,0}, acc11 = {0,0,0,0};
    #pragma unroll 4
    for (int kk = 0; kk < NN; kk += 32){
        ux2i q0 = *(const ux2i*)(adj8 + aoff + kk);
        ux2i q1 = *(const ux2i*)(adj8 + aoff + 16*NN + kk);
        fx2 f0 = __builtin_amdgcn_cvt_pk_f32_fp8((int)q0[0], false);
        fx2 f1 = __builtin_amdgcn_cvt_pk_f32_fp8((int)q0[0], true);
        fx2 f2 = __builtin_amdgcn_cvt_pk_f32_fp8((int)q0[1], false);
        fx2 f3 = __builtin_amdgcn_cvt_pk_f32_fp8((int)q0[1], true);
        fx2 g0 = __builtin_amdgcn_cvt_pk_f32_fp8((int)q1[0], false);
        fx2 g1 = __builtin_amdgcn_cvt_pk_f32_fp8((int)q1[0], true);
        fx2 g2 = __builtin_amdgcn_cvt_pk_f32_fp8((int)q1[1], false);
        fx2 g3 = __builtin_amdgcn_cvt_pk_f32_fp8((int)q1[1], true);
        union { unsigned u[4]; sx8 s; } A0, A1;
        A0.u[0] = cvt_pk_bf16(f0[0], f0[1]);
        A0.u[1] = cvt_pk_bf16(f1[0], f1[1]);
        A0.u[2] = cvt_pk_bf16(f2[0], f2[1]);
        A0.u[3] = cvt_pk_bf16(f3[0], f3[1]);
        A1.u[0] = cvt_pk_bf16(g0[0], g0[1]);
        A1.u[1] = cvt_pk_bf16(g1[0], g1[1]);
        A1.u[2] = cvt_pk_bf16(g2[0], g2[1]);
        A1.u[3] = cvt_pk_bf16(g3[0], g3[1]);
        int kb = (kk + lk) * 2;
        sx8 b0 = *(const sx8*)((const char*)uts + ((c0*2048 + kb) ^ ((c0 & 7) << 4)));
        sx8 b1 = *(const sx8*)((const char*)uts + ((c1*2048 + kb) ^ ((c1 & 7) << 4)));
        acc00 = __builtin_amdgcn_mfma_f32_16x16x32_bf16(A0.s, b0, acc00, 0, 0, 0);
        acc01 = __builtin_amdgcn_mfma_f32_16x16x32_bf16(A0.s, b1, acc01, 0, 0, 0);
        acc10 = __builtin_amdgcn_mfma_f32_16x16x32_bf16(A1.s, b0, acc10, 0, 0, 0);
        acc11 = __builtin_amdgcn_mfma_f32_16x16x32_bf16(A1.s, b1, acc11, 0, 0, 0);
    }
    int lq = l >> 4;
    #pragma unroll
    for (int mt = 0; mt < 2; mt++){
        int rl0 = w*32 + mt*16 + lq*4;
        fx4 am0 = mt ? acc10 : acc00;
        fx4 am1 = mt ? acc11 : acc01;
        #pragma unroll
        for (int ct = 0; ct < 2; ct++){
            fx4 a = ct ? am1 : am0;
            int col = ct ? c1 : c0;
            #pragma unroll
            for (int j = 0; j < 4; j++)
                vls[rl0 + j][col] = f2bf(a[j]);    // v1 true (enc pre-scaled)
        }
    }
    __syncthreads();
    // h2 = relu(v1@Wd1 + bd1) * 2^-14; 2 threads/row, 15 cols each
    int row = tid >> 1, half = tid & 1;
    float v[18];
    #pragma unroll
    for (int j = 0; j < 18; j++) v[j] = bf2f(vls[row][j]);
    float acc2[15];
    #pragma unroll
    for (int c = 0; c < 15; c++) acc2[c] = 0.f;
    #pragma unroll
    for (int j = 0; j < 18; j++){
        #pragma unroll
        for (int c = 0; c < 15; c++) acc2[c] += v[j]*wd[j*30 + half*15 + c];
    }
    unsigned short* base = h2T + (size_t)b*32*NN + rt*128 + row;
    #pragma unroll
    for (int c = 0; c < 15; c++){
        int cc = half*15 + c;
        base[(size_t)cc*NN] = f2bf(fmaxf(acc2[c] + bdl[cc], 0.f)*INV_SCALE);
    }
    base[(size_t)(30 + half)*NN] = 0;              // zero pad cols 30,31
}

// --- FUSED final: v2 = adj@h2 (LDS) ; dec/sampled/logp epilogue (k_dec bounce) ---
// Requires adj8 NOT aliasing dec/sampled (adj8 in d_ws). Grid (4,B) x 512 threads.
__global__ __launch_bounds__(512) void k_v2dec(
    const unsigned char* __restrict__ adj8,
    const unsigned short* __restrict__ h2T,
    const float* __restrict__ Wd2, const float* __restrict__ bd2,
    const int* __restrict__ masks, const float* __restrict__ noise,
    float* __restrict__ dec, float* __restrict__ sampled, float* __restrict__ part){
    __shared__ __align__(16) char smem[94464];
    __shared__ float red[8];
    unsigned short* uts = (unsigned short*)smem;              // phase1 (64KB)
    unsigned short* wls = (unsigned short*)smem;              // phase2 (40960B)
    float (*dls)[516]   = (float(*)[516])(smem + 40960);      // phase2 (33024B)
    unsigned short* v2ls = (unsigned short*)(smem + 73984);   // both (20480B)
    int tid = threadIdx.x;
    int rt = blockIdx.x, b = blockIdx.y;
    int w = tid >> 6, l = tid & 63;
    int lr = l & 15, kq = l >> 4, lk = kq*8;
    // ---- phase 1: stage h2T, v2 = adj@h2 into v2ls ----
    const ux4i* src = (const ux4i*)(h2T + (size_t)b*32*NN);
    #pragma unroll
    for (int i = 0; i < 8; i++){
        int j = tid + i*512;
        int c = j >> 7;
        ux4i v = src[j];
        *(ux4i*)((char*)uts + ((j*16) ^ ((c & 7) << 4))) = v;
    }
    __syncthreads();
    size_t aoff = (size_t)b*NN*NN + (size_t)(rt*256 + w*32 + lr)*NN + lk;
    int c0 = lr, c1 = 16 + lr;
    fx4 acc00 = {0,0,0,0}, acc01 = {0,0,0,0}, acc10 = {0,0,0,0}, acc11 = {0,0,0,0};
    #pragma unroll 4
    for (int kk = 0; kk < NN; kk += 32){
        ux2i q0 = *(const ux2i*)(adj8 + aoff + kk);
        ux2i q1 = *(const ux2i*)(adj8 + aoff + 16*NN + kk);
        fx2 f0 = __builtin_amdgcn_cvt_pk_f32_fp8((int)q0[0], false);
        fx2 f1 = __builtin_amdgcn_cvt_pk_f32_fp8((int)q0[0], true);
        fx2 f2 = __builtin_amdgcn_cvt_pk_f32_fp8((int)q0[1], false);
        fx2 f3 = __builtin_amdgcn_cvt_pk_f32_fp8((int)q0[1], true);
        fx2 g0 = __builtin_amdgcn_cvt_pk_f32_fp8((int)q1[0], false);
        fx2 g1 = __builtin_amdgcn_cvt_pk_f32_fp8((int)q1[0], true);
        fx2 g2 = __builtin_amdgcn_cvt_pk_f32_fp8((int)q1[1], false);
        fx2 g3 = __builtin_amdgcn_cvt_pk_f32_fp8((int)q1[1], true);
        union { unsigned u[4]; sx8 s; } A0, A1;
        A0.u[0] = cvt_pk_bf16(f0[0], f0[1]);
        A0.u[1] = cvt_pk_bf16(f1[0], f1[1]);
        A0.u[2] = cvt_pk_bf16(f2[0], f2[1]);
        A0.u[3] = cvt_pk_bf16(f3[0], f3[1]);
        A1.u[0] = cvt_pk_bf16(g0[0], g0[1]);
        A1.u[1] = cvt_pk_bf16(g1[0], g1[1]);
        A1.u[2] = cvt_pk_bf16(g2[0], g2[1]);
        A1.u[3] = cvt_pk_bf16(g3[0], g3[1]);
        int kb = (kk + lk) * 2;
        sx8 b0 = *(const sx8*)((const char*)uts + ((c0*2048 + kb) ^ ((c0 & 7) << 4)));
        sx8 b1 = *(const sx8*)((const char*)uts + ((c1*2048 + kb) ^ ((c1 & 7) << 4)));
        acc00 = __builtin_amdgcn_mfma_f32_16x16x32_bf16(A0.s, b0, acc00, 0, 0, 0);
        acc01 = __builtin_amdgcn_mfma_f32_16x16x32_bf16(A0.s, b1, acc01, 0, 0, 0);
        acc10 = __builtin_amdgcn_mfma_f32_16x16x32_bf16(A1.s, b0, acc10, 0, 0, 0);
        acc11 = __builtin_amdgcn_mfma_f32_16x16x32_bf16(A1.s, b1, acc11, 0, 0, 0);
    }
    #pragma unroll
    for (int mt = 0; mt < 2; mt++){
        int rl0 = w*32 + mt*16 + kq*4;
        fx4 am0 = mt ? acc10 : acc00;
        fx4 am1 = mt ? acc11 : acc01;
        #pragma unroll
        for (int ct = 0; ct < 2; ct++){
            fx4 a = ct ? am1 : am0;
            int col = ct ? c1 : c0;
            #pragma unroll
            for (int j = 0; j < 4; j++)
                v2ls[(rl0 + j)*40 + col] = f2bf(a[j]);   // v2 true
        }
    }
    __syncthreads();                       // uts reads done; safe to overwrite
    // ---- phase 2: stage Wd2^T into wls ----
    for (int i = tid; i < 512*32; i += 512){
        int col = i & 511, k = i >> 9;
        float v = (k < 30) ? Wd2[k*512 + col] : 0.f;
        wls[col*40 + k] = f2bf(v);
    }
    __syncthreads();
    const float LPC = 2.9930844722234733f; // -log(sigma) - 0.5*log(2*pi)
    float lpacc = 0.f;
    int growbase = b*NN + rt*256;
    for (int it = 0; it < 16; it++){
        int rb = it*16;
        size_t offA = (size_t)(growbase + rb + w)*FF + l*8;
        size_t offB = offA + (size_t)8*FF;
        ix4 mA0 = ntload((const ix4*)(masks + offA));
        ix4 mA1 = ntload((const ix4*)(masks + offA + 4));
        fx4 zA0 = ntload((const fx4*)(noise + offA));
        fx4 zA1 = ntload((const fx4*)(noise + offA + 4));
        ix4 mB0 = ntload((const ix4*)(masks + offB));
        ix4 mB1 = ntload((const ix4*)(masks + offB + 4));
        fx4 zB0 = ntload((const fx4*)(noise + offB));
        fx4 zB1 = ntload((const fx4*)(noise + offB + 4));
        sx8 a = *(const sx8*)(v2ls + (rb + lr)*40 + kq*8);
        #pragma unroll
        for (int i = 0; i < 4; i++){
            int c = (w + 8*i)*16 + lr;
            sx8 bb = *(const sx8*)(wls + c*40 + kq*8);
            fx4 acc = {0,0,0,0};
            acc = __builtin_amdgcn_mfma_f32_16x16x32_bf16(a, bb, acc, 0, 0, 0);
            float bi = bd2[c];
            #pragma unroll
            for (int j = 0; j < 4; j++)
                dls[kq*4 + j][c] = acc[j] + bi;
        }
        __syncthreads();
        #pragma unroll
        for (int s = 0; s < 2; s++){
            int rloc = s ? (w + 8) : w;
            size_t off = s ? offB : offA;
            ix4 m0 = s ? mB0 : mA0;  ix4 m1 = s ? mB1 : mA1;
            fx4 z0 = s ? zB0 : zA0;  fx4 z1 = s ? zB1 : zA1;
            fx4 d0 = *(const fx4*)&dls[rloc][l*8];
            fx4 d1 = *(const fx4*)&dls[rloc][l*8 + 4];
            float av[8];
            #pragma unroll
            for (int i = 0; i < 4; i++){
                av[i]   = 1.f/(1.f + __expf(-d0[i]));
                av[4+i] = 1.f/(1.f + __expf(-d1[i]));
            }
            if (l < 4){                    // cols 0..31 -> softmax
                float mx = d0[0];
                #pragma unroll
                for (int i = 1; i < 4; i++) mx = fmaxf(mx, d0[i]);
                #pragma unroll
                for (int i = 0; i < 4; i++) mx = fmaxf(mx, d1[i]);
                mx = fmaxf(mx, __shfl_xor(mx, 1, 4));
                mx = fmaxf(mx, __shfl_xor(mx, 2, 4));
                float e[8], ss = 0.f;
                #pragma unroll
                for (int i = 0; i < 4; i++){ e[i] = __expf(d0[i] - mx); ss += e[i]; }
                #pragma unroll
                for (int i = 0; i < 4; i++){ e[4+i] = __expf(d1[i] - mx); ss += e[4+i]; }
                ss += __shfl_xor(ss, 1, 4);
                ss += __shfl_xor(ss, 2, 4);
                float inv = 1.f / ss;
                #pragma unroll
                for (int i = 0; i < 8; i++) av[i] = e[i]*inv;
            }
            ntstore4(dec + off,     d0);
            ntstore4(dec + off + 4, d1);
            fx4 sm0, sm1;
            #pragma unroll
            for (int i = 0; i < 4; i++){
                float mi0 = (float)m0[i], zi0 = z0[i];
                float mi1 = (float)m1[i], zi1 = z1[i];
                sm0[i] = av[i]   + mi0*(0.02f*zi0);
                sm1[i] = av[4+i] + mi1*(0.02f*zi1);
                lpacc = fmaf(mi0, LPC - 0.5f*zi0*zi0, lpacc);
                lpacc = fmaf(mi1, LPC - 0.5f*zi1*zi1, lpacc);
            }
            ntstore4(sampled + off,     sm0);
            ntstore4(sampled + off + 4, sm1);
        }
        __syncthreads();
    }
    #pragma unroll
    for (int off = 32; off > 0; off >>= 1) lpacc += __shfl_xor(lpacc, off);
    if (l == 0) red[w] = lpacc;
    __syncthreads();
    if (tid == 0){
        float s = 0.f;
        #pragma unroll
        for (int i = 0; i < 8; i++) s += red[i];
        part[blockIdx.y*4 + blockIdx.x] = s;
    }
}

// ---------------- fallback k_dec (round-8 version) ----------------
__global__ __launch_bounds__(512, 2) void k_dec(
    const unsigned short* __restrict__ v2R,
    const float* __restrict__ Wd2, const float* __restrict__ bd2,
    const int* __restrict__ masks, const float* __restrict__ noise,
    float* __restrict__ dec, float* __restrict__ sampled, float* __restrict__ part){
    __shared__ unsigned short wls[512*40];
    __shared__ float dls[16][516];
    __shared__ float red[8];
    int tid = threadIdx.x;
    for (int i = tid; i < 512*32; i += 512){
        int col = i & 511, k = i >> 9;
        float v = (k < 30) ? Wd2[k*512 + col] : 0.f;
        wls[col*40 + k] = f2bf(v);
    }
    int w = tid >> 6, l = tid & 63;
    int lr = l & 15, kq = l >> 4;
    const float LPC = 2.9930844722234733f;
    float lpacc = 0.f;
    __syncthreads();
    #pragma unroll
    for (int it = 0; it < 4; it++){
        int rbase = blockIdx.x*64 + it*16;
        size_t offA = (size_t)(rbase + w)*FF + l*8;
        size_t offB = (size_t)(rbase + w + 8)*FF + l*8;
        ix4 mA0 = ntload((const ix4*)(masks + offA));
        ix4 mA1 = ntload((const ix4*)(masks + offA + 4));
        fx4 zA0 = ntload((const fx4*)(noise + offA));
        fx4 zA1 = ntload((const fx4*)(noise + offA + 4));
        ix4 mB0 = ntload((const ix4*)(masks + offB));
        ix4 mB1 = ntload((const ix4*)(masks + offB + 4));
        fx4 zB0 = ntload((const fx4*)(noise + offB));
        fx4 zB1 = ntload((const fx4*)(noise + offB + 4));
        sx8 a = *(const sx8*)(v2R + (size_t)(rbase + lr)*32 + kq*8);
        #pragma unroll
        for (int i = 0; i < 4; i++){
            int c = (w + 8*i)*16 + lr;
            sx8 bb = *(const sx8*)(wls + c*40 + kq*8);
            fx4 acc = {0,0,0,0};
            acc = __builtin_amdgcn_mfma_f32_16x16x32_bf16(a, bb, acc, 0, 0, 0);
            float bi = bd2[c];
            #pragma unroll
            for (int j = 0; j < 4; j++)
                dls[kq*4 + j][c] = acc[j] + bi;
        }
        __syncthreads();
        #pragma unroll
        for (int s = 0; s < 2; s++){
            int rloc = s ? (w + 8) : w;
            size_t off = s ? offB : offA;
            ix4 m0 = s ? mB0 : mA0;  ix4 m1 = s ? mB1 : mA1;
            fx4 z0 = s ? zB0 : zA0;  fx4 z1 = s ? zB1 : zA1;
            fx4 d0 = *(const fx4*)&dls[rloc][l*8];
            fx4 d1 = *(const fx4*)&dls[rloc][l*8 + 4];
            float av[8];
            #pragma unroll
            for (int i = 0; i < 4; i++){
                av[i]   = 1.f/(1.f + __expf(-d0[i]));
                av[4+i] = 1.f/(1.f + __expf(-d1[i]));
            }
            if (l < 4){
                float mx = d0[0];
                #pragma unroll
                for (int i = 1; i < 4; i++) mx = fmaxf(mx, d0[i]);
                #pragma unroll
                for (int i = 0; i < 4; i++) mx = fmaxf(mx, d1[i]);
                mx = fmaxf(mx, __shfl_xor(mx, 1, 4));
                mx = fmaxf(mx, __shfl_xor(mx, 2, 4));
                float e[8], ss = 0.f;
                #pragma unroll
                for (int i = 0; i < 4; i++){ e[i] = __expf(d0[i] - mx); ss += e[i]; }
                #pragma unroll
                for (int i = 0; i < 4; i++){ e[4+i] = __expf(d1[i] - mx); ss += e[4+i]; }
                ss += __shfl_xor(ss, 1, 4);
                ss += __shfl_xor(ss, 2, 4);
                float inv = 1.f / ss;
                #pragma unroll
                for (int i = 0; i < 8; i++) av[i] = e[i]*inv;
            }
            ntstore4(dec + off,     d0);
            ntstore4(dec + off + 4, d1);
            fx4 sm0, sm1;
            #pragma unroll
            for (int i = 0; i < 4; i++){
                float mi0 = (float)m0[i], zi0 = z0[i];
                float mi1 = (float)m1[i], zi1 = z1[i];
                sm0[i] = av[i]   + mi0*(0.02f*zi0);
                sm1[i] = av[4+i] + mi1*(0.02f*zi1);
                lpacc = fmaf(mi0, LPC - 0.5f*zi0*zi0, lpacc);
                lpacc = fmaf(mi1, LPC - 0.5f*zi1*zi1, lpacc);
            }
            ntstore4(sampled + off,     sm0);
            ntstore4(sampled + off + 4, sm1);
        }
        __syncthreads();
    }
    #pragma unroll
    for (int off = 32; off > 0; off >>= 1) lpacc += __shfl_xor(lpacc, off);
    if (l == 0) red[w] = lpacc;
    __syncthreads();
    if (tid == 0){
        float s = 0.f;
        #pragma unroll
        for (int i = 0; i < 8; i++) s += red[i];
        part[blockIdx.x] = s;
    }
}

// ---------------- final: logp[b] = sum of PB block partials ----------------
template<int PB>
__global__ void k_lp(const float* __restrict__ part, float* __restrict__ logp){
    int t = threadIdx.x;   // 64 threads, one per batch
    float s = 0.f;
    #pragma unroll
    for (int i = 0; i < PB; i++) s += part[t*PB + i];
    logp[t] = s;
}

extern "C" void kernel_launch(void* const* d_in, const int* in_sizes, int n_in,
                              void* d_out, int out_size, void* d_ws, size_t ws_size,
                              hipStream_t stream){
    const float* x     = (const float*)d_in[0];
    const float* adj   = (const float*)d_in[1];
    const int*   masks = (const int*)  d_in[2];
    const float* noise = (const float*)d_in[3];
    const float* We1   = (const float*)d_in[4];
    const float* be1   = (const float*)d_in[5];
    const float* We2   = (const float*)d_in[6];
    const float* be2   = (const float*)d_in[7];
    const float* Wd1   = (const float*)d_in[8];
    const float* bd1   = (const float*)d_in[9];
    const float* Wd2   = (const float*)d_in[10];
    const float* bd2   = (const float*)d_in[11];

    float* dec     = (float*)d_out;
    float* sampled = dec + (size_t)B_*NN*FF;
    float* logp    = sampled + (size_t)B_*NN*FF;

    const size_t ADJ8_BYTES = (size_t)B_*NN*NN;         // 64 MiB... (67,108,864 B)
    const size_t BUF_ELEMS  = (size_t)B_*32*NN;         // 2M bf16 = 4 MB
    bool bigws = ws_size >= ADJ8_BYTES + 4*BUF_ELEMS + 1024;

    unsigned char* adj8;
    unsigned short *bufA, *bufB;
    if (bigws){
        adj8 = (unsigned char*)d_ws;
        bufA = (unsigned short*)((char*)d_ws + ADJ8_BYTES);
        bufB = bufA + BUF_ELEMS;
    } else {
        adj8 = (unsigned char*)d_out;   // dec region, dead until final kernel
        bufA = (unsigned short*)d_ws;
        bufB = bufA + BUF_ELEMS;
    }

    k_xw1<<<dim3(8, B_), 512, 0, stream>>>(x, We1, bufA);                               // u1
    k_cvt_h1u2<<<dim3(8, B_), 256, 0, stream>>>(adj, adj8, bufA, be1, We2, bufB);       // adj8 + u2_s
    k_adjf8<0><<<dim3(8, B_), 256, 0, stream>>>(adj8, bufB, be2, 18, INV_SCALE, bufA);  // enc_s
    k_v1h2<<<dim3(8, B_), 256, 0, stream>>>(adj8, bufA, Wd1, bd1, bufB);                // h2_s
    if (bigws){
        float* part = (float*)bufA;     // enc dead after k_v1h2
        k_v2dec<<<dim3(4, B_), 512, 0, stream>>>(adj8, bufB, Wd2, bd2, masks, noise,
                                                 dec, sampled, part);
        k_lp<4><<<1, 64, 0, stream>>>(part, logp);
    } else {
        float* part = (float*)bufB;     // safe after h2 consumed by v2 pass
        k_adjf8<1><<<dim3(8, B_), 256, 0, stream>>>(adj8, bufB, nullptr, 0, 1.0f, bufA); // v2 RM
        k_dec<<<1024, 512, 0, stream>>>(bufA, Wd2, bd2, masks, noise, dec, sampled, part);
        k_lp<16><<<1, 64, 0, stream>>>(part, logp);
    }
}

// Round 10
// 322.469 us; speedup vs baseline: 1.1481x; 1.0195x over previous
//
#include <hip/hip_runtime.h>

#define B_ 64
#define NN 1024
#define FF 512

typedef float  fx4 __attribute__((ext_vector_type(4)));
typedef float  fx2 __attribute__((ext_vector_type(2)));
typedef int    ix4 __attribute__((ext_vector_type(4)));
typedef unsigned int   ux4i __attribute__((ext_vector_type(4)));
typedef unsigned int   ux2i __attribute__((ext_vector_type(2)));
typedef unsigned short us4  __attribute__((ext_vector_type(4)));
typedef short  sx8 __attribute__((ext_vector_type(8)));

#define FP8_SCALE   16384.0f        // 2^14: adj*2^14 in [0,16] -> e4m3 normal range
#define INV_SCALE   6.103515625e-5f // 2^-14, folded into operands (exact pow2)

static __device__ __forceinline__ unsigned short f2bf(float f){
    union { float f; unsigned u; } v; v.f = f;
    unsigned r = v.u + 0x7FFFu + ((v.u >> 16) & 1u);   // RTNE
    return (unsigned short)(r >> 16);
}
static __device__ __forceinline__ float bf2f(unsigned short h){
    union { unsigned u; float f; } v; v.u = ((unsigned)h) << 16;
    return v.f;
}
static __device__ __forceinline__ unsigned cvt_pk_bf16(float lo, float hi){
    unsigned r;
    asm("v_cvt_pk_bf16_f32 %0, %1, %2" : "=v"(r) : "v"(lo), "v"(hi));
    return r;
}
static __device__ __forceinline__ sx8 pack_bf16x8(fx4 v0, fx4 v1){
    union { unsigned u[4]; sx8 s; } r;
    r.u[0] = cvt_pk_bf16(v0[0], v0[1]);
    r.u[1] = cvt_pk_bf16(v0[2], v0[3]);
    r.u[2] = cvt_pk_bf16(v1[0], v1[1]);
    r.u[3] = cvt_pk_bf16(v1[2], v1[3]);
    return r.s;
}
template<typename T>
static __device__ __forceinline__ T ntload(const T* p){ return __builtin_nontemporal_load(p); }
static __device__ __forceinline__ void ntstore4(float* p, fx4 v){
    __builtin_nontemporal_store(v, (fx4*)p);
}

// ---------------- u1 = x @ We1 via MFMA, write bf16 transposed [B][32][1024] ----
__global__ __launch_bounds__(512) void k_xw1(
    const float* __restrict__ x, const float* __restrict__ We1,
    unsigned short* __restrict__ u1T){
    __shared__ unsigned short wls[32*512];     // 32 KB
    int tid = threadIdx.x;
    for (int i = tid; i < 32*512; i += 512){
        int col = i >> 9, k = i & 511;
        float v = (col < 30) ? We1[k*30 + col] : 0.f;
        wls[col*512 + ((((k >> 3) ^ (col & 7)) << 3) | (k & 7))] = f2bf(v);
    }
    __syncthreads();
    int w = tid >> 6, l = tid & 63;
    int lr = l & 15, kq = l >> 4;
    int b = blockIdx.y;
    int rowb = blockIdx.x*128 + w*16;
    const float* xp = x + ((size_t)b*NN + rowb + lr)*FF + kq*8;
    fx4 acc0 = {0,0,0,0}, acc1 = {0,0,0,0};
    int c0 = lr, c1 = 16 + lr;
    #pragma unroll 4
    for (int kk = 0; kk < FF; kk += 32){
        fx4 v0 = ntload((const fx4*)(xp + kk));
        fx4 v1 = ntload((const fx4*)(xp + kk + 4));
        sx8 a = pack_bf16x8(v0, v1);
        int chunk = (kk >> 3) + kq;
        sx8 b0 = *(const sx8*)(wls + c0*512 + ((chunk ^ (c0 & 7)) << 3));
        sx8 b1 = *(const sx8*)(wls + c1*512 + ((chunk ^ (c1 & 7)) << 3));
        acc0 = __builtin_amdgcn_mfma_f32_16x16x32_bf16(a, b0, acc0, 0, 0, 0);
        acc1 = __builtin_amdgcn_mfma_f32_16x16x32_bf16(a, b1, acc1, 0, 0, 0);
    }
    int row0 = rowb + kq*4;
    us4 o0 = { f2bf(acc0[0]), f2bf(acc0[1]), f2bf(acc0[2]), f2bf(acc0[3]) };
    us4 o1 = { f2bf(acc1[0]), f2bf(acc1[1]), f2bf(acc1[2]), f2bf(acc1[3]) };
    *(us4*)(u1T + ((size_t)b*32 + c0)*NN + row0) = o0;
    *(us4*)(u1T + ((size_t)b*32 + c1)*NN + row0) = o1;
}

// -- pass 1 fused: h1 = relu(adj@u1+be1) (LDS only) ; u2 = h1@We2 * 2^-14 -> u2T --
__global__ __launch_bounds__(256) void k_cvt_h1u2(
    const float* __restrict__ adjf, unsigned char* __restrict__ adj8,
    const unsigned short* __restrict__ uT, const float* __restrict__ be1,
    const float* __restrict__ We2, unsigned short* __restrict__ u2T){
    __shared__ unsigned short uts[32*NN];      // 64 KB
    __shared__ unsigned short hls[128][34];    // 8704 B
    __shared__ float wels[540];                // We2 30x18
    int tid = threadIdx.x;
    int rt = blockIdx.x, b = blockIdx.y;
    for (int i = tid; i < 540; i += 256) wels[i] = We2[i];
    const ux4i* src = (const ux4i*)(uT + (size_t)b*32*NN);
    #pragma unroll
    for (int i = 0; i < 16; i++){
        int j = tid + i*256;
        int c = j >> 7;
        ux4i v = src[j];
        *(ux4i*)((char*)uts + ((j*16) ^ ((c & 7) << 4))) = v;
    }
    __syncthreads();
    int w = tid >> 6, l = tid & 63;
    int lr = l & 15, lk = (l >> 4) * 8;
    size_t aoff = (size_t)b*NN*NN + (size_t)(rt*128 + w*32 + lr)*NN + lk;
    int c0 = lr, c1 = 16 + lr;
    fx4 acc00 = {0,0,0,0}, acc01 = {0,0,0,0}, acc10 = {0,0,0,0}, acc11 = {0,0,0,0};
    #pragma unroll 4
    for (int kk = 0; kk < NN; kk += 32){
        fx4 v00 = ntload((const fx4*)(adjf + aoff + kk));
        fx4 v01 = ntload((const fx4*)(adjf + aoff + kk + 4));
        fx4 v10 = ntload((const fx4*)(adjf + aoff + 16*NN + kk));
        fx4 v11 = ntload((const fx4*)(adjf + aoff + 16*NN + kk + 4));
        sx8 a0 = pack_bf16x8(v00, v01);
        sx8 a1 = pack_bf16x8(v10, v11);
        {
            const float S = FP8_SCALE;
            int d0 = __builtin_amdgcn_cvt_pk_fp8_f32(v00[0]*S, v00[1]*S, 0, false);
            d0     = __builtin_amdgcn_cvt_pk_fp8_f32(v00[2]*S, v00[3]*S, d0, true);
            int d1 = __builtin_amdgcn_cvt_pk_fp8_f32(v01[0]*S, v01[1]*S, 0, false);
            d1     = __builtin_amdgcn_cvt_pk_fp8_f32(v01[2]*S, v01[3]*S, d1, true);
            ux2i s0 = { (unsigned)d0, (unsigned)d1 };
            *(ux2i*)(adj8 + aoff + kk) = s0;
            int d2 = __builtin_amdgcn_cvt_pk_fp8_f32(v10[0]*S, v10[1]*S, 0, false);
            d2     = __builtin_amdgcn_cvt_pk_fp8_f32(v10[2]*S, v10[3]*S, d2, true);
            int d3 = __builtin_amdgcn_cvt_pk_fp8_f32(v11[0]*S, v11[1]*S, 0, false);
            d3     = __builtin_amdgcn_cvt_pk_fp8_f32(v11[2]*S, v11[3]*S, d3, true);
            ux2i s1 = { (unsigned)d2, (unsigned)d3 };
            *(ux2i*)(adj8 + aoff + 16*NN + kk) = s1;
        }
        int kb = (kk + lk) * 2;
        sx8 b0 = *(const sx8*)((const char*)uts + ((c0*2048 + kb) ^ ((c0 & 7) << 4)));
        sx8 b1 = *(const sx8*)((const char*)uts + ((c1*2048 + kb) ^ ((c1 & 7) << 4)));
        acc00 = __builtin_amdgcn_mfma_f32_16x16x32_bf16(a0, b0, acc00, 0, 0, 0);
        acc01 = __builtin_amdgcn_mfma_f32_16x16x32_bf16(a0, b1, acc01, 0, 0, 0);
        acc10 = __builtin_amdgcn_mfma_f32_16x16x32_bf16(a1, b0, acc10, 0, 0, 0);
        acc11 = __builtin_amdgcn_mfma_f32_16x16x32_bf16(a1, b1, acc11, 0, 0, 0);
    }
    float bias0 = (c0 < 30) ? be1[c0] : 0.f;
    float bias1 = (c1 < 30) ? be1[c1] : 0.f;
    int lq = l >> 4;
    #pragma unroll
    for (int mt = 0; mt < 2; mt++){
        int rl0 = w*32 + mt*16 + lq*4;
        fx4 am0 = mt ? acc10 : acc00;
        fx4 am1 = mt ? acc11 : acc01;
        #pragma unroll
        for (int ct = 0; ct < 2; ct++){
            fx4 a = ct ? am1 : am0;
            float bb = ct ? bias1 : bias0;
            int col = ct ? c1 : c0;
            #pragma unroll
            for (int j = 0; j < 4; j++)
                hls[rl0 + j][col] = f2bf(fmaxf(a[j] + bb, 0.f));
        }
    }
    __syncthreads();
    // u2 = h1 @ We2, scaled 2^-14; rows split 2 threads/row, 9 cols each
    int row = tid >> 1, half = tid & 1;
    float h[30];
    #pragma unroll
    for (int j = 0; j < 30; j++) h[j] = bf2f(hls[row][j]);
    float acc2[9] = {0,0,0,0,0,0,0,0,0};
    #pragma unroll
    for (int j = 0; j < 30; j++){
        #pragma unroll
        for (int c = 0; c < 9; c++) acc2[c] += h[j]*wels[j*18 + half*9 + c];
    }
    unsigned short* base = u2T + (size_t)b*32*NN + rt*128 + row;
    #pragma unroll
    for (int c = 0; c < 9; c++)
        base[(size_t)(half*9 + c)*NN] = f2bf(acc2[c]*INV_SCALE);
    #pragma unroll
    for (int i = 0; i < 7; i++)
        base[(size_t)(18 + half*7 + i)*NN] = 0;   // zero pad cols 18..31
}

// ------- fp8 adj pass: out = (2^14*adj_q) @ U_scaled (+bias), oscale on write ----
template<int RM>
__global__ __launch_bounds__(256) void k_adjf8(
    const unsigned char* __restrict__ adj8,
    const unsigned short* __restrict__ uT,
    const float* __restrict__ bias, int biasN, float oscale,
    unsigned short* __restrict__ outT){
    __shared__ unsigned short uts[32*NN];
    int tid = threadIdx.x;
    int rt = blockIdx.x, b = blockIdx.y;
    const ux4i* src = (const ux4i*)(uT + (size_t)b*32*NN);
    #pragma unroll
    for (int i = 0; i < 16; i++){
        int j = tid + i*256;
        int c = j >> 7;
        ux4i v = src[j];
        *(ux4i*)((char*)uts + ((j*16) ^ ((c & 7) << 4))) = v;
    }
    __syncthreads();
    int w = tid >> 6, l = tid & 63;
    int lr = l & 15, lk = (l >> 4) * 8;
    size_t aoff = (size_t)b*NN*NN + (size_t)(rt*128 + w*32 + lr)*NN + lk;
    int c0 = lr, c1 = 16 + lr;
    fx4 acc00 = {0,0,0,0}, acc01 = {0,0,0,0}, acc10 = {0,0,0,0}, acc11 = {0,0,0,0};
    #pragma unroll 4
    for (int kk = 0; kk < NN; kk += 32){
        ux2i q0 = *(const ux2i*)(adj8 + aoff + kk);
        ux2i q1 = *(const ux2i*)(adj8 + aoff + 16*NN + kk);
        fx2 f0 = __builtin_amdgcn_cvt_pk_f32_fp8((int)q0[0], false);
        fx2 f1 = __builtin_amdgcn_cvt_pk_f32_fp8((int)q0[0], true);
        fx2 f2 = __builtin_amdgcn_cvt_pk_f32_fp8((int)q0[1], false);
        fx2 f3 = __builtin_amdgcn_cvt_pk_f32_fp8((int)q0[1], true);
        fx2 g0 = __builtin_amdgcn_cvt_pk_f32_fp8((int)q1[0], false);
        fx2 g1 = __builtin_amdgcn_cvt_pk_f32_fp8((int)q1[0], true);
        fx2 g2 = __builtin_amdgcn_cvt_pk_f32_fp8((int)q1[1], false);
        fx2 g3 = __builtin_amdgcn_cvt_pk_f32_fp8((int)q1[1], true);
        union { unsigned u[4]; sx8 s; } A0, A1;
        A0.u[0] = cvt_pk_bf16(f0[0], f0[1]);
        A0.u[1] = cvt_pk_bf16(f1[0], f1[1]);
        A0.u[2] = cvt_pk_bf16(f2[0], f2[1]);
        A0.u[3] = cvt_pk_bf16(f3[0], f3[1]);
        A1.u[0] = cvt_pk_bf16(g0[0], g0[1]);
        A1.u[1] = cvt_pk_bf16(g1[0], g1[1]);
        A1.u[2] = cvt_pk_bf16(g2[0], g2[1]);
        A1.u[3] = cvt_pk_bf16(g3[0], g3[1]);
        int kb = (kk + lk) * 2;
        sx8 b0 = *(const sx8*)((const char*)uts + ((c0*2048 + kb) ^ ((c0 & 7) << 4)));
        sx8 b1 = *(const sx8*)((const char*)uts + ((c1*2048 + kb) ^ ((c1 & 7) << 4)));
        acc00 = __builtin_amdgcn_mfma_f32_16x16x32_bf16(A0.s, b0, acc00, 0, 0, 0);
        acc01 = __builtin_amdgcn_mfma_f32_16x16x32_bf16(A0.s, b1, acc01, 0, 0, 0);
        acc10 = __builtin_amdgcn_mfma_f32_16x16x32_bf16(A1.s, b0, acc10, 0, 0, 0);
        acc11 = __builtin_amdgcn_mfma_f32_16x16x32_bf16(A1.s, b1, acc11, 0, 0, 0);
    }
    float bias0 = 0.f, bias1 = 0.f;
    if (bias){
        if (c0 < biasN) bias0 = bias[c0];
        if (c1 < biasN) bias1 = bias[c1];
    }
    int lq = l >> 4;
    #pragma unroll
    for (int mt = 0; mt < 2; mt++){
        int row0 = rt*128 + w*32 + mt*16 + lq*4;
        fx4 am0 = mt ? acc10 : acc00;
        fx4 am1 = mt ? acc11 : acc01;
        #pragma unroll
        for (int ct = 0; ct < 2; ct++){
            fx4 a = ct ? am1 : am0;
            float bb = ct ? bias1 : bias0;
            int col = ct ? c1 : c0;
            us4 o;
            #pragma unroll
            for (int j = 0; j < 4; j++){
                float v = (a[j] + bb) * oscale;
                o[j] = f2bf(v);
            }
            if (RM){
                #pragma unroll
                for (int j = 0; j < 4; j++)
                    outT[((size_t)b*NN + row0 + j)*32 + col] = o[j];
            } else {
                *(us4*)(outT + ((size_t)b*32 + col)*NN + row0) = o;
            }
        }
    }
}

// -- v1 pass fused: v1 = adj@enc (LDS only) ; h2 = relu(v1@Wd1+bd1)*2^-14 -> h2T --
__global__ __launch_bounds__(256) void k_v1h2(
    const unsigned char* __restrict__ adj8,
    const unsigned short* __restrict__ encT,
    const float* __restrict__ Wd1, const float* __restrict__ bd1,
    unsigned short* __restrict__ h2T){
    __shared__ unsigned short uts[32*NN];
    __shared__ unsigned short vls[128][34];
    __shared__ float wd[540];                  // Wd1 18x30
    __shared__ float bdl[30];
    int tid = threadIdx.x;
    int rt = blockIdx.x, b = blockIdx.y;
    for (int i = tid; i < 540; i += 256) wd[i] = Wd1[i];
    if (tid < 30) bdl[tid] = bd1[tid];
    const ux4i* src = (const ux4i*)(encT + (size_t)b*32*NN);
    #pragma unroll
    for (int i = 0; i < 16; i++){
        int j = tid + i*256;
        int c = j >> 7;
        ux4i v = src[j];
        *(ux4i*)((char*)uts + ((j*16) ^ ((c & 7) << 4))) = v;
    }
    __syncthreads();
    int w = tid >> 6, l = tid & 63;
    int lr = l & 15, lk = (l >> 4) * 8;
    size_t aoff = (size_t)b*NN*NN + (size_t)(rt*128 + w*32 + lr)*NN + lk;
    int c0 = lr, c1 = 16 + lr;
    fx4 acc00 = {0,0,0,0}, acc01 = {0,0,0,0}, acc10 = {0,0,0,0}, acc11 = {0,0,0,0};
    #pragma unroll 4
    for (int kk = 0; kk < NN; kk += 32){
        ux2i q0 = *(const ux2i*)(adj8 + aoff + kk);
        ux2i q1 = *(const ux2i*)(adj8 + aoff + 16*NN + kk);
        fx2 f0 = __builtin_amdgcn_cvt_pk_f32_fp8((int)q0[0], false);
        fx2 f1 = __builtin_amdgcn_cvt_pk_f32_fp8((int)q0[0], true);
        fx2 f2 = __builtin_amdgcn_cvt_pk_f32_fp8((int)q0[1], false);
        fx2 f3 = __builtin_amdgcn_cvt_pk_f32_fp8((int)q0[1], true);
        fx2 g0 = __builtin_amdgcn_cvt_pk_f32_fp8((int)q1[0], false);
        fx2 g1 = __builtin_amdgcn_cvt_pk_f32_fp8((int)q1[0], true);
        fx2 g2 = __builtin_amdgcn_cvt_pk_f32_fp8((int)q1[1], false);
        fx2 g3 = __builtin_amdgcn_cvt_pk_f32_fp8((int)q1[1], true);
        union { unsigned u[4]; sx8 s; } A0, A1;
        A0.u[0] = cvt_pk_bf16(f0[0], f0[1]);
        A0.u[1] = cvt_pk_bf16(f1[0], f1[1]);
        A0.u[2] = cvt_pk_bf16(f2[0], f2[1]);
        A0.u[3] = cvt_pk_bf16(f3[0], f3[1]);
        A1.u[0] = cvt_pk_bf16(g0[0], g0[1]);
        A1.u[1] = cvt_pk_bf16(g1[0], g1[1]);
        A1.u[2] = cvt_pk_bf16(g2[0], g2[1]);
        A1.u[3] = cvt_pk_bf16(g3[0], g3[1]);
        int kb = (kk + lk) * 2;
        sx8 b0 = *(const sx8*)((const char*)uts + ((c0*2048 + kb) ^ ((c0 & 7) << 4)));
        sx8 b1 = *(const sx8*)((const char*)uts + ((c1*2048 + kb) ^ ((c1 & 7) << 4)));
        acc00 = __builtin_amdgcn_mfma_f32_16x16x32_bf16(A0.s, b0, acc00, 0, 0, 0);
        acc01 = __builtin_amdgcn_mfma_f32_16x16x32_bf16(A0.s, b1, acc01, 0, 0, 0);
        acc10 = __builtin_amdgcn_mfma_f32_16x16x32_bf16(A1.s, b0, acc10, 0, 0, 0);
        acc11 = __builtin_amdgcn_mfma_f32_16x16x32_bf16(A1.s, b1, acc11, 0, 0, 0);
    }
    int lq = l >> 4;
    #pragma unroll
    for (int mt = 0; mt < 2; mt++){
        int rl0 = w*32 + mt*16 + lq*4;
        fx4 am0 = mt ? acc10 : acc00;
        fx4 am1 = mt ? acc11 : acc01;
        #pragma unroll
        for (int ct = 0; ct < 2; ct++){
            fx4 a = ct ? am1 : am0;
            int col = ct ? c1 : c0;
            #pragma unroll
            for (int j = 0; j < 4; j++)
                vls[rl0 + j][col] = f2bf(a[j]);    // v1 true (enc pre-scaled)
        }
    }
    __syncthreads();
    // h2 = relu(v1@Wd1 + bd1) * 2^-14; 2 threads/row, 15 cols each
    int row = tid >> 1, half = tid & 1;
    float v[18];
    #pragma unroll
    for (int j = 0; j < 18; j++) v[j] = bf2f(vls[row][j]);
    float acc2[15];
    #pragma unroll
    for (int c = 0; c < 15; c++) acc2[c] = 0.f;
    #pragma unroll
    for (int j = 0; j < 18; j++){
        #pragma unroll
        for (int c = 0; c < 15; c++) acc2[c] += v[j]*wd[j*30 + half*15 + c];
    }
    unsigned short* base = h2T + (size_t)b*32*NN + rt*128 + row;
    #pragma unroll
    for (int c = 0; c < 15; c++){
        int cc = half*15 + c;
        base[(size_t)cc*NN] = f2bf(fmaxf(acc2[c] + bdl[cc], 0.f)*INV_SCALE);
    }
    base[(size_t)(30 + half)*NN] = 0;              // zero pad cols 30,31
}

// --- FUSED final: v2 = adj@h2 (LDS) ; dec/sampled/logp epilogue ---
// 1024 threads (16 waves) to double latency-hiding at 1 block/CU.
__global__ __launch_bounds__(1024) void k_v2dec(
    const unsigned char* __restrict__ adj8,
    const unsigned short* __restrict__ h2T,
    const float* __restrict__ Wd2, const float* __restrict__ bd2,
    const int* __restrict__ masks, const float* __restrict__ noise,
    float* __restrict__ dec, float* __restrict__ sampled, float* __restrict__ part){
    __shared__ __align__(16) char smem[94464];
    __shared__ float red[16];
    unsigned short* uts = (unsigned short*)smem;              // phase1 (64KB)
    unsigned short* wls = (unsigned short*)smem;              // phase2 (40960B)
    float (*dls)[516]   = (float(*)[516])(smem + 40960);      // phase2 (33024B)
    unsigned short* v2ls = (unsigned short*)(smem + 73984);   // both (20480B)
    int tid = threadIdx.x;
    int rt = blockIdx.x, b = blockIdx.y;
    int w = tid >> 6, l = tid & 63;                            // w in 0..15
    int lr = l & 15, kq = l >> 4, lk = kq*8;
    // ---- phase 1: stage h2T, v2 = adj@h2 into v2ls (16 waves x 16 rows) ----
    const ux4i* src = (const ux4i*)(h2T + (size_t)b*32*NN);
    #pragma unroll
    for (int i = 0; i < 4; i++){
        int j = tid + i*1024;
        int c = j >> 7;
        ux4i v = src[j];
        *(ux4i*)((char*)uts + ((j*16) ^ ((c & 7) << 4))) = v;
    }
    __syncthreads();
    size_t aoff = (size_t)b*NN*NN + (size_t)(rt*256 + w*16 + lr)*NN + lk;
    int c0 = lr, c1 = 16 + lr;
    fx4 acc00 = {0,0,0,0}, acc01 = {0,0,0,0};
    #pragma unroll 4
    for (int kk = 0; kk < NN; kk += 32){
        ux2i q0 = *(const ux2i*)(adj8 + aoff + kk);
        fx2 f0 = __builtin_amdgcn_cvt_pk_f32_fp8((int)q0[0], false);
        fx2 f1 = __builtin_amdgcn_cvt_pk_f32_fp8((int)q0[0], true);
        fx2 f2 = __builtin_amdgcn_cvt_pk_f32_fp8((int)q0[1], false);
        fx2 f3 = __builtin_amdgcn_cvt_pk_f32_fp8((int)q0[1], true);
        union { unsigned u[4]; sx8 s; } A0;
        A0.u[0] = cvt_pk_bf16(f0[0], f0[1]);
        A0.u[1] = cvt_pk_bf16(f1[0], f1[1]);
        A0.u[2] = cvt_pk_bf16(f2[0], f2[1]);
        A0.u[3] = cvt_pk_bf16(f3[0], f3[1]);
        int kb = (kk + lk) * 2;
        sx8 b0 = *(const sx8*)((const char*)uts + ((c0*2048 + kb) ^ ((c0 & 7) << 4)));
        sx8 b1 = *(const sx8*)((const char*)uts + ((c1*2048 + kb) ^ ((c1 & 7) << 4)));
        acc00 = __builtin_amdgcn_mfma_f32_16x16x32_bf16(A0.s, b0, acc00, 0, 0, 0);
        acc01 = __builtin_amdgcn_mfma_f32_16x16x32_bf16(A0.s, b1, acc01, 0, 0, 0);
    }
    {
        int rl0 = w*16 + kq*4;
        #pragma unroll
        for (int ct = 0; ct < 2; ct++){
            fx4 a = ct ? acc01 : acc00;
            int col = ct ? c1 : c0;
            #pragma unroll
            for (int j = 0; j < 4; j++)
                v2ls[(rl0 + j)*40 + col] = f2bf(a[j]);   // v2 true
        }
    }
    __syncthreads();                       // uts reads done; safe to overwrite
    // ---- phase 2: stage Wd2^T into wls ----
    for (int i = tid; i < 512*32; i += 1024){
        int col = i & 511, k = i >> 9;
        float v = (k < 30) ? Wd2[k*512 + col] : 0.f;
        wls[col*40 + k] = f2bf(v);
    }
    __syncthreads();
    const float LPC = 2.9930844722234733f; // -log(sigma) - 0.5*log(2*pi)
    float lpacc = 0.f;
    int growbase = b*NN + rt*256;
    for (int it = 0; it < 16; it++){
        int rb = it*16;
        // wave w streams ONE row this iteration: prefetch its masks/noise early
        size_t offA = (size_t)(growbase + rb + w)*FF + l*8;
        ix4 mA0 = ntload((const ix4*)(masks + offA));
        ix4 mA1 = ntload((const ix4*)(masks + offA + 4));
        fx4 zA0 = ntload((const fx4*)(noise + offA));
        fx4 zA1 = ntload((const fx4*)(noise + offA + 4));
        sx8 a = *(const sx8*)(v2ls + (rb + lr)*40 + kq*8);
        #pragma unroll
        for (int i = 0; i < 2; i++){
            int c = (w + 16*i)*16 + lr;
            sx8 bb = *(const sx8*)(wls + c*40 + kq*8);
            fx4 acc = {0,0,0,0};
            acc = __builtin_amdgcn_mfma_f32_16x16x32_bf16(a, bb, acc, 0, 0, 0);
            float bi = bd2[c];
            #pragma unroll
            for (int j = 0; j < 4; j++)
                dls[kq*4 + j][c] = acc[j] + bi;
        }
        __syncthreads();
        {
            fx4 d0 = *(const fx4*)&dls[w][l*8];
            fx4 d1 = *(const fx4*)&dls[w][l*8 + 4];
            float av[8];
            #pragma unroll
            for (int i = 0; i < 4; i++){
                av[i]   = 1.f/(1.f + __expf(-d0[i]));
                av[4+i] = 1.f/(1.f + __expf(-d1[i]));
            }
            if (l < 4){                    // cols 0..31 -> softmax
                float mx = d0[0];
                #pragma unroll
                for (int i = 1; i < 4; i++) mx = fmaxf(mx, d0[i]);
                #pragma unroll
                for (int i = 0; i < 4; i++) mx = fmaxf(mx, d1[i]);
                mx = fmaxf(mx, __shfl_xor(mx, 1, 4));
                mx = fmaxf(mx, __shfl_xor(mx, 2, 4));
                float e[8], ss = 0.f;
                #pragma unroll
                for (int i = 0; i < 4; i++){ e[i] = __expf(d0[i] - mx); ss += e[i]; }
                #pragma unroll
                for (int i = 0; i < 4; i++){ e[4+i] = __expf(d1[i] - mx); ss += e[4+i]; }
                ss += __shfl_xor(ss, 1, 4);
                ss += __shfl_xor(ss, 2, 4);
                float inv = 1.f / ss;
                #pragma unroll
                for (int i = 0; i < 8; i++) av[i] = e[i]*inv;
            }
            ntstore4(dec + offA,     d0);
            ntstore4(dec + offA + 4, d1);
            fx4 sm0, sm1;
            #pragma unroll
            for (int i = 0; i < 4; i++){
                float mi0 = (float)mA0[i], zi0 = zA0[i];
                float mi1 = (float)mA1[i], zi1 = zA1[i];
                sm0[i] = av[i]   + mi0*(0.02f*zi0);
                sm1[i] = av[4+i] + mi1*(0.02f*zi1);
                lpacc = fmaf(mi0, LPC - 0.5f*zi0*zi0, lpacc);
                lpacc = fmaf(mi1, LPC - 0.5f*zi1*zi1, lpacc);
            }
            ntstore4(sampled + offA,     sm0);
            ntstore4(sampled + offA + 4, sm1);
        }
        __syncthreads();
    }
    #pragma unroll
    for (int off = 32; off > 0; off >>= 1) lpacc += __shfl_xor(lpacc, off);
    if (l == 0) red[w] = lpacc;
    __syncthreads();
    if (tid == 0){
        float s = 0.f;
        #pragma unroll
        for (int i = 0; i < 16; i++) s += red[i];
        part[blockIdx.y*4 + blockIdx.x] = s;
    }
}

// ---------------- fallback k_dec (round-8 version) ----------------
__global__ __launch_bounds__(512, 2) void k_dec(
    const unsigned short* __restrict__ v2R,
    const float* __restrict__ Wd2, const float* __restrict__ bd2,
    const int* __restrict__ masks, const float* __restrict__ noise,
    float* __restrict__ dec, float* __restrict__ sampled, float* __restrict__ part){
    __shared__ unsigned short wls[512*40];
    __shared__ float dls[16][516];
    __shared__ float red[8];
    int tid = threadIdx.x;
    for (int i = tid; i < 512*32; i += 512){
        int col = i & 511, k = i >> 9;
        float v = (k < 30) ? Wd2[k*512 + col] : 0.f;
        wls[col*40 + k] = f2bf(v);
    }
    int w = tid >> 6, l = tid & 63;
    int lr = l & 15, kq = l >> 4;
    const float LPC = 2.9930844722234733f;
    float lpacc = 0.f;
    __syncthreads();
    #pragma unroll
    for (int it = 0; it < 4; it++){
        int rbase = blockIdx.x*64 + it*16;
        size_t offA = (size_t)(rbase + w)*FF + l*8;
        size_t offB = (size_t)(rbase + w + 8)*FF + l*8;
        ix4 mA0 = ntload((const ix4*)(masks + offA));
        ix4 mA1 = ntload((const ix4*)(masks + offA + 4));
        fx4 zA0 = ntload((const fx4*)(noise + offA));
        fx4 zA1 = ntload((const fx4*)(noise + offA + 4));
        ix4 mB0 = ntload((const ix4*)(masks + offB));
        ix4 mB1 = ntload((const ix4*)(masks + offB + 4));
        fx4 zB0 = ntload((const fx4*)(noise + offB));
        fx4 zB1 = ntload((const fx4*)(noise + offB + 4));
        sx8 a = *(const sx8*)(v2R + (size_t)(rbase + lr)*32 + kq*8);
        #pragma unroll
        for (int i = 0; i < 4; i++){
            int c = (w + 8*i)*16 + lr;
            sx8 bb = *(const sx8*)(wls + c*40 + kq*8);
            fx4 acc = {0,0,0,0};
            acc = __builtin_amdgcn_mfma_f32_16x16x32_bf16(a, bb, acc, 0, 0, 0);
            float bi = bd2[c];
            #pragma unroll
            for (int j = 0; j < 4; j++)
                dls[kq*4 + j][c] = acc[j] + bi;
        }
        __syncthreads();
        #pragma unroll
        for (int s = 0; s < 2; s++){
            int rloc = s ? (w + 8) : w;
            size_t off = s ? offB : offA;
            ix4 m0 = s ? mB0 : mA0;  ix4 m1 = s ? mB1 : mA1;
            fx4 z0 = s ? zB0 : zA0;  fx4 z1 = s ? zB1 : zA1;
            fx4 d0 = *(const fx4*)&dls[rloc][l*8];
            fx4 d1 = *(const fx4*)&dls[rloc][l*8 + 4];
            float av[8];
            #pragma unroll
            for (int i = 0; i < 4; i++){
                av[i]   = 1.f/(1.f + __expf(-d0[i]));
                av[4+i] = 1.f/(1.f + __expf(-d1[i]));
            }
            if (l < 4){
                float mx = d0[0];
                #pragma unroll
                for (int i = 1; i < 4; i++) mx = fmaxf(mx, d0[i]);
                #pragma unroll
                for (int i = 0; i < 4; i++) mx = fmaxf(mx, d1[i]);
                mx = fmaxf(mx, __shfl_xor(mx, 1, 4));
                mx = fmaxf(mx, __shfl_xor(mx, 2, 4));
                float e[8], ss = 0.f;
                #pragma unroll
                for (int i = 0; i < 4; i++){ e[i] = __expf(d0[i] - mx); ss += e[i]; }
                #pragma unroll
                for (int i = 0; i < 4; i++){ e[4+i] = __expf(d1[i] - mx); ss += e[4+i]; }
                ss += __shfl_xor(ss, 1, 4);
                ss += __shfl_xor(ss, 2, 4);
                float inv = 1.f / ss;
                #pragma unroll
                for (int i = 0; i < 8; i++) av[i] = e[i]*inv;
            }
            ntstore4(dec + off,     d0);
            ntstore4(dec + off + 4, d1);
            fx4 sm0, sm1;
            #pragma unroll
            for (int i = 0; i < 4; i++){
                float mi0 = (float)m0[i], zi0 = z0[i];
                float mi1 = (float)m1[i], zi1 = z1[i];
                sm0[i] = av[i]   + mi0*(0.02f*zi0);
                sm1[i] = av[4+i] + mi1*(0.02f*zi1);
                lpacc = fmaf(mi0, LPC - 0.5f*zi0*zi0, lpacc);
                lpacc = fmaf(mi1, LPC - 0.5f*zi1*zi1, lpacc);
            }
            ntstore4(sampled + off,     sm0);
            ntstore4(sampled + off + 4, sm1);
        }
        __syncthreads();
    }
    #pragma unroll
    for (int off = 32; off > 0; off >>= 1) lpacc += __shfl_xor(lpacc, off);
    if (l == 0) red[w] = lpacc;
    __syncthreads();
    if (tid == 0){
        float s = 0.f;
        #pragma unroll
        for (int i = 0; i < 8; i++) s += red[i];
        part[blockIdx.x] = s;
    }
}

// ---------------- final: logp[b] = sum of PB block partials ----------------
template<int PB>
__global__ void k_lp(const float* __restrict__ part, float* __restrict__ logp){
    int t = threadIdx.x;   // 64 threads, one per batch
    float s = 0.f;
    #pragma unroll
    for (int i = 0; i < PB; i++) s += part[t*PB + i];
    logp[t] = s;
}

extern "C" void kernel_launch(void* const* d_in, const int* in_sizes, int n_in,
                              void* d_out, int out_size, void* d_ws, size_t ws_size,
                              hipStream_t stream){
    const float* x     = (const float*)d_in[0];
    const float* adj   = (const float*)d_in[1];
    const int*   masks = (const int*)  d_in[2];
    const float* noise = (const float*)d_in[3];
    const float* We1   = (const float*)d_in[4];
    const float* be1   = (const float*)d_in[5];
    const float* We2   = (const float*)d_in[6];
    const float* be2   = (const float*)d_in[7];
    const float* Wd1   = (const float*)d_in[8];
    const float* bd1   = (const float*)d_in[9];
    const float* Wd2   = (const float*)d_in[10];
    const float* bd2   = (const float*)d_in[11];

    float* dec     = (float*)d_out;
    float* sampled = dec + (size_t)B_*NN*FF;
    float* logp    = sampled + (size_t)B_*NN*FF;

    const size_t ADJ8_BYTES = (size_t)B_*NN*NN;         // 67,108,864 B
    const size_t BUF_ELEMS  = (size_t)B_*32*NN;         // 2M bf16 = 4 MB
    bool bigws = ws_size >= ADJ8_BYTES + 4*BUF_ELEMS + 1024;

    unsigned char* adj8;
    unsigned short *bufA, *bufB;
    if (bigws){
        adj8 = (unsigned char*)d_ws;
        bufA = (unsigned short*)((char*)d_ws + ADJ8_BYTES);
        bufB = bufA + BUF_ELEMS;
    } else {
        adj8 = (unsigned char*)d_out;   // dec region, dead until final kernel
        bufA = (unsigned short*)d_ws;
        bufB = bufA + BUF_ELEMS;
    }

    k_xw1<<<dim3(8, B_), 512, 0, stream>>>(x, We1, bufA);                               // u1
    k_cvt_h1u2<<<dim3(8, B_), 256, 0, stream>>>(adj, adj8, bufA, be1, We2, bufB);       // adj8 + u2_s
    k_adjf8<0><<<dim3(8, B_), 256, 0, stream>>>(adj8, bufB, be2, 18, INV_SCALE, bufA);  // enc_s
    k_v1h2<<<dim3(8, B_), 256, 0, stream>>>(adj8, bufA, Wd1, bd1, bufB);                // h2_s
    if (bigws){
        float* part = (float*)bufA;     // enc dead after k_v1h2
        k_v2dec<<<dim3(4, B_), 1024, 0, stream>>>(adj8, bufB, Wd2, bd2, masks, noise,
                                                  dec, sampled, part);
        k_lp<4><<<1, 64, 0, stream>>>(part, logp);
    } else {
        float* part = (float*)bufB;     // safe after h2 consumed by v2 pass
        k_adjf8<1><<<dim3(8, B_), 256, 0, stream>>>(adj8, bufB, nullptr, 0, 1.0f, bufA); // v2 RM
        k_dec<<<1024, 512, 0, stream>>>(bufA, Wd2, bd2, masks, noise, dec, sampled, part);
        k_lp<16><<<1, 64, 0, stream>>>(part, logp);
    }
}